// Round 1
// baseline (8481.480 us; speedup 1.0000x reference)
//
#include <hip/hip_runtime.h>
#include <hip/hip_bf16.h>
#include <cstdint>
#include <cstddef>

#define T_SEQ   2048
#define HIDDEN  5120
#define NH      32
#define DQ      128
#define DR      64
#define DV      128
#define Q_LORA  1536
#define KV_LORA 512
#define QD      (DQ + DR)          // 192
#define KVD     (KV_LORA + DR)     // 576
#define QROW    (NH * QD)          // 6144
#define KVUPROW (NH * (DQ + DV))   // 8192
#define AOROW   (NH * DV)          // 4096

// ---------------------------------------------------------------------------
// Generic guarded fp32 GEMM: C[M,N] = A[M,K] @ B[K,N].
// 128x128 tile, BK=8, 256 threads, 8x8 micro-tile per thread.
// M must be %128, K %8; N guarded (needed for N=576).
// ---------------------------------------------------------------------------
__global__ __launch_bounds__(256) void gemm_f32(
    const float* __restrict__ A, const float* __restrict__ B,
    float* __restrict__ C, int M, int N, int K, int lda, int ldb, int ldc)
{
    __shared__ float As[8][128];   // As[k][m] (transposed for broadcast reads)
    __shared__ float Bs[8][128];   // Bs[k][n]

    const int tid  = threadIdx.x;
    const int bm   = blockIdx.y * 128;
    const int bn   = blockIdx.x * 128;
    const int arow = tid >> 1;           // 0..127
    const int acol = (tid & 1) << 2;     // 0 or 4
    const int brow = tid >> 5;           // 0..7
    const int bcol = (tid & 31) << 2;    // 0..124
    const int tx   = tid & 15;
    const int ty   = tid >> 4;

    float acc[8][8] = {};

    const float* Aptr = A + (size_t)(bm + arow) * lda + acol;

    for (int k0 = 0; k0 < K; k0 += 8) {
        float4 av = *(const float4*)(Aptr + k0);                 // M%128==0, K%8==0: in-bounds
        float4 bv = make_float4(0.f, 0.f, 0.f, 0.f);
        if (bn + bcol + 4 <= N)
            bv = *(const float4*)(B + (size_t)(k0 + brow) * ldb + bn + bcol);

        __syncthreads();   // previous iteration's compute done
        As[acol + 0][arow] = av.x;
        As[acol + 1][arow] = av.y;
        As[acol + 2][arow] = av.z;
        As[acol + 3][arow] = av.w;
        *(float4*)&Bs[brow][bcol] = bv;
        __syncthreads();

#pragma unroll
        for (int kk = 0; kk < 8; ++kk) {
            float a[8], b[8];
#pragma unroll
            for (int i = 0; i < 8; ++i) a[i] = As[kk][ty * 8 + i];
#pragma unroll
            for (int j = 0; j < 8; ++j) b[j] = Bs[kk][tx * 8 + j];
#pragma unroll
            for (int i = 0; i < 8; ++i)
#pragma unroll
                for (int j = 0; j < 8; ++j)
                    acc[i][j] += a[i] * b[j];
        }
    }

#pragma unroll
    for (int i = 0; i < 8; ++i) {
        const int row = bm + ty * 8 + i;
#pragma unroll
        for (int j = 0; j < 8; ++j) {
            const int col = bn + tx * 8 + j;
            if (col < N) C[(size_t)row * ldc + col] = acc[i][j];
        }
    }
}

// ---------------------------------------------------------------------------
// In-place RMSNorm over the first `len` columns of each `stride`-wide row.
// One 256-thread block per row.
// ---------------------------------------------------------------------------
__global__ __launch_bounds__(256) void rmsnorm_k(
    float* __restrict__ x, const float* __restrict__ g, int len, int stride)
{
    float* xr = x + (size_t)blockIdx.x * stride;
    float ss = 0.f;
    for (int i = threadIdx.x; i < len; i += 256) {
        float v = xr[i];
        ss += v * v;
    }
    // wave64 reduce then cross-wave via LDS
#pragma unroll
    for (int off = 32; off > 0; off >>= 1) ss += __shfl_down(ss, off);
    __shared__ float red[4];
    if ((threadIdx.x & 63) == 0) red[threadIdx.x >> 6] = ss;
    __syncthreads();
    float tot = red[0] + red[1] + red[2] + red[3];
    float scale = rsqrtf(tot / (float)len + 1e-6f);
    for (int i = threadIdx.x; i < len; i += 256) xr[i] = xr[i] * scale * g[i];
}

// ---------------------------------------------------------------------------
// RoPE (GPT-J interleaved rotate, NEOX concatenated cos/sin):
//   angle(pos, j) = pos * theta^(-(j&31)/32),  j = element index in 0..63
//   out[2i]   = x[2i]  *cos(a(2i))   - x[2i+1]*sin(a(2i))
//   out[2i+1] = x[2i+1]*cos(a(2i+1)) + x[2i]  *sin(a(2i+1))
// ---------------------------------------------------------------------------
#define ROPE_LN_THETA_OVER_32 0.28782313662425575f  // ln(10000)/32

__device__ __forceinline__ void rope_pair(float p, int i, float& x0, float& x1)
{
    const int   j0 = (2 * i) & 31;
    const int   j1 = (2 * i + 1) & 31;
    const float a0 = p * expf(-(float)j0 * ROPE_LN_THETA_OVER_32);
    const float a1 = p * expf(-(float)j1 * ROPE_LN_THETA_OVER_32);
    const float r0 = x0 * cosf(a0) - x1 * sinf(a0);
    const float r1 = x1 * cosf(a1) + x0 * sinf(a1);
    x0 = r0; x1 = r1;
}

__global__ __launch_bounds__(256) void rope_q_k(
    float* __restrict__ q, const int* __restrict__ pos)
{
    const int idx = blockIdx.x * 256 + threadIdx.x;  // t*1024 + h*32 + i
    const int i = idx & 31;
    const int h = (idx >> 5) & 31;
    const int t = idx >> 10;
    float* base = q + (size_t)t * QROW + h * QD + DQ;
    float x0 = base[2 * i], x1 = base[2 * i + 1];
    rope_pair((float)pos[t], i, x0, x1);
    base[2 * i] = x0;
    base[2 * i + 1] = x1;
}

__global__ __launch_bounds__(256) void rope_k_k(
    float* __restrict__ kv, const int* __restrict__ pos)
{
    const int idx = blockIdx.x * 256 + threadIdx.x;  // t*32 + i
    const int i = idx & 31;
    const int t = idx >> 5;
    float* base = kv + (size_t)t * KVD + KV_LORA;
    float x0 = base[2 * i], x1 = base[2 * i + 1];
    rope_pair((float)pos[t], i, x0, x1);
    base[2 * i] = x0;
    base[2 * i + 1] = x1;
}

// ---------------------------------------------------------------------------
// Flash-style causal attention.
// Block = 256 threads handles (head h, 32 query rows). K-tiles of 32 keys.
// Thread t: q-row = t/8, owns 4 keys (t%8)*4.. for scores, and 16 V-dims
// (t%8)*16.. for the output accumulator. Online softmax state (m,l) kept
// redundantly per thread (identical across the 8 threads of a row).
// ---------------------------------------------------------------------------
__global__ __launch_bounds__(256) void attn_k(
    const float* __restrict__ q, const float* __restrict__ kvup,
    const float* __restrict__ kv, float* __restrict__ out)
{
    const int h  = blockIdx.x;
    const int qb = blockIdx.y;
    const int q0 = qb * 32;

    __shared__ float Qs[32][192];
    __shared__ float Ks[32][192];
    __shared__ float Vs[32][128];
    __shared__ float Ps[32][32];
    __shared__ float redm[32][8];
    __shared__ float reds[32][8];

    const int tid = threadIdx.x;
    const int qr  = tid >> 3;        // 0..31
    const int kg  = tid & 7;         // 0..7
    const int kb  = kg * 4;          // first of 4 keys this thread scores
    const int dv0 = kg * 16;         // first of 16 V dims this thread owns

    const float scale = 0.07216878364870322f;  // (DQ+DR)^-0.5 = 1/sqrt(192)

    for (int idx = tid; idx < 32 * 192; idx += 256) {
        int r = idx / 192, d = idx % 192;
        Qs[r][d] = q[(size_t)(q0 + r) * QROW + h * QD + d] * scale;
    }

    float m_run = -1e30f, l_run = 0.f;
    float acc[16] = {};

    for (int kt = 0; kt <= qb; ++kt) {
        __syncthreads();  // previous tile's readers done (also covers Qs store)
        for (int idx = tid; idx < 32 * 192; idx += 256) {
            int r = idx / 192, d = idx % 192;
            int k = kt * 32 + r;
            Ks[r][d] = (d < 128)
                ? kvup[(size_t)k * KVUPROW + h * (DQ + DV) + d]          // k_nope
                : kv[(size_t)k * KVD + KV_LORA + (d - 128)];             // k_pe (roped)
        }
        for (int idx = tid; idx < 32 * 128; idx += 256) {
            int r = idx >> 7, d = idx & 127;
            Vs[r][d] = kvup[(size_t)(kt * 32 + r) * KVUPROW + h * (DQ + DV) + 128 + d];
        }
        __syncthreads();

        // 4 scores per thread (Q row reused across the 4 keys)
        float s[4] = {0.f, 0.f, 0.f, 0.f};
        for (int d = 0; d < 192; d += 4) {
            float4 qv = *(const float4*)&Qs[qr][d];
#pragma unroll
            for (int jj = 0; jj < 4; ++jj) {
                float4 kvv = *(const float4*)&Ks[kb + jj][d];
                s[jj] += qv.x * kvv.x + qv.y * kvv.y + qv.z * kvv.z + qv.w * kvv.w;
            }
        }

        bool valid[4];
        float tmax = -1e30f;
#pragma unroll
        for (int jj = 0; jj < 4; ++jj) {
            valid[jj] = (kt * 32 + kb + jj) <= (q0 + qr);
            if (!valid[jj]) s[jj] = -1e30f;
            tmax = fmaxf(tmax, s[jj]);
        }
        redm[qr][kg] = tmax;
        __syncthreads();

        float tile_max = redm[qr][0];
#pragma unroll
        for (int w = 1; w < 8; ++w) tile_max = fmaxf(tile_max, redm[qr][w]);
        const float new_m = fmaxf(m_run, tile_max);   // tile always has >=1 valid key
        const float alpha = expf(m_run - new_m);

        float psum = 0.f;
#pragma unroll
        for (int jj = 0; jj < 4; ++jj) {
            float pv = valid[jj] ? expf(s[jj] - new_m) : 0.f;
            Ps[qr][kb + jj] = pv;
            psum += pv;
        }
        reds[qr][kg] = psum;
        __syncthreads();

        float sum8 = 0.f;
#pragma unroll
        for (int w = 0; w < 8; ++w) sum8 += reds[qr][w];
        l_run = l_run * alpha + sum8;
        m_run = new_m;

#pragma unroll
        for (int j = 0; j < 16; ++j) acc[j] *= alpha;
        for (int kk = 0; kk < 32; ++kk) {
            const float pv = Ps[qr][kk];
#pragma unroll
            for (int j4 = 0; j4 < 4; ++j4) {
                float4 vv = *(const float4*)&Vs[kk][dv0 + j4 * 4];
                acc[j4 * 4 + 0] += pv * vv.x;
                acc[j4 * 4 + 1] += pv * vv.y;
                acc[j4 * 4 + 2] += pv * vv.z;
                acc[j4 * 4 + 3] += pv * vv.w;
            }
        }
    }

    const float inv_l = 1.f / l_run;
    float* op = out + (size_t)(q0 + qr) * AOROW + h * DV + dv0;
#pragma unroll
    for (int j = 0; j < 16; ++j) op[j] = acc[j] * inv_l;
}

// ---------------------------------------------------------------------------
extern "C" void kernel_launch(void* const* d_in, const int* in_sizes, int n_in,
                              void* d_out, int out_size, void* d_ws, size_t ws_size,
                              hipStream_t stream)
{
    const int*   positions = (const int*)d_in[0];
    const float* hidden    = (const float*)d_in[1];
    const float* w_qa      = (const float*)d_in[2];
    const float* gamma_q   = (const float*)d_in[3];
    const float* w_qb      = (const float*)d_in[4];
    const float* w_kva     = (const float*)d_in[5];
    const float* gamma_kv  = (const float*)d_in[6];
    const float* w_kvb     = (const float*)d_in[7];
    const float* w_o       = (const float*)d_in[8];
    float*       out       = (float*)d_out;

    // Workspace layout (fp32): total ~168.3 MB
    float* qa   = (float*)d_ws;                       // [2048,1536]
    float* qbuf = qa   + (size_t)T_SEQ * Q_LORA;      // [2048,6144]
    float* kvb  = qbuf + (size_t)T_SEQ * QROW;        // [2048,576]
    float* kvup = kvb  + (size_t)T_SEQ * KVD;         // [2048,8192]
    float* aout = kvup + (size_t)T_SEQ * KVUPROW;     // [2048,4096]

    const dim3 blk(256);

    // 1) qa = hidden @ w_qa
    gemm_f32<<<dim3(Q_LORA / 128, T_SEQ / 128), blk, 0, stream>>>(
        hidden, w_qa, qa, T_SEQ, Q_LORA, HIDDEN, HIDDEN, Q_LORA, Q_LORA);
    // 2) rmsnorm(qa) in place
    rmsnorm_k<<<dim3(T_SEQ), blk, 0, stream>>>(qa, gamma_q, Q_LORA, Q_LORA);
    // 3) qbuf = qa @ w_qb
    gemm_f32<<<dim3(QROW / 128, T_SEQ / 128), blk, 0, stream>>>(
        qa, w_qb, qbuf, T_SEQ, QROW, Q_LORA, Q_LORA, QROW, QROW);
    // 4) kvb = hidden @ w_kva   (N=576 -> guarded tiles)
    gemm_f32<<<dim3((KVD + 127) / 128, T_SEQ / 128), blk, 0, stream>>>(
        hidden, w_kva, kvb, T_SEQ, KVD, HIDDEN, HIDDEN, KVD, KVD);
    // 5) rmsnorm on kvb[:, :512] in place (row stride 576)
    rmsnorm_k<<<dim3(T_SEQ), blk, 0, stream>>>(kvb, gamma_kv, KV_LORA, KVD);
    // 6) RoPE on k_pe (kvb cols 512..575), in place
    rope_k_k<<<dim3(T_SEQ * 32 / 256), blk, 0, stream>>>(kvb, positions);
    // 7) kvup = kv_c @ w_kvb  (A = kvb with lda=576, K=512)
    gemm_f32<<<dim3(KVUPROW / 128, T_SEQ / 128), blk, 0, stream>>>(
        kvb, w_kvb, kvup, T_SEQ, KVUPROW, KV_LORA, KVD, KVUPROW, KVUPROW);
    // 8) RoPE on q_pe (qbuf cols 128..191 of each head), in place
    rope_q_k<<<dim3(T_SEQ * NH * 32 / 256), blk, 0, stream>>>(qbuf, positions);
    // 9) causal flash attention -> aout [2048, 4096]
    attn_k<<<dim3(NH, T_SEQ / 32), blk, 0, stream>>>(qbuf, kvup, kvb, aout);
    // 10) out = aout @ w_o
    gemm_f32<<<dim3(HIDDEN / 128, T_SEQ / 128), blk, 0, stream>>>(
        aout, w_o, out, T_SEQ, HIDDEN, AOROW, AOROW, HIDDEN, HIDDEN);
}

// Round 2
// 5510.702 us; speedup vs baseline: 1.5391x; 1.5391x over previous
//
#include <hip/hip_runtime.h>
#include <hip/hip_bf16.h>
#include <cstdint>
#include <cstddef>

#define T_SEQ   2048
#define HIDDEN  5120
#define NH      32
#define DQ      128
#define DR      64
#define DV      128
#define Q_LORA  1536
#define KV_LORA 512
#define QD      (DQ + DR)          // 192
#define KVD     (KV_LORA + DR)     // 576
#define QROW    (NH * QD)          // 6144
#define KVUPROW (NH * (DQ + DV))   // 8192
#define AOROW   (NH * DV)          // 4096

// ---------------------------------------------------------------------------
// Generic guarded fp32 GEMM: C[M,N] = A[M,K] @ B[K,N].
// 128x128 tile, BK=8, 256 threads, 8x8 micro-tile per thread.
// B-fragment per thread = two float4 groups at cols {4*tx, 64+4*tx} so that
// an 8-lane phase hits 8 distinct bank-groups (was 8*tx -> 4-way conflict).
// M must be %128, K %8; N guarded (needed for N=576).
// ---------------------------------------------------------------------------
__global__ __launch_bounds__(256) void gemm_f32(
    const float* __restrict__ A, const float* __restrict__ B,
    float* __restrict__ C, int M, int N, int K, int lda, int ldb, int ldc)
{
    __shared__ float As[8][128];   // As[k][m] (transposed for broadcast reads)
    __shared__ float Bs[8][128];   // Bs[k][n]

    const int tid  = threadIdx.x;
    const int bm   = blockIdx.y * 128;
    const int bn   = blockIdx.x * 128;
    const int arow = tid >> 1;           // 0..127
    const int acol = (tid & 1) << 2;     // 0 or 4
    const int brow = tid >> 5;           // 0..7
    const int bcol = (tid & 31) << 2;    // 0..124
    const int tx   = tid & 15;
    const int ty   = tid >> 4;

    float acc[8][8] = {};

    const float* Aptr = A + (size_t)(bm + arow) * lda + acol;

    for (int k0 = 0; k0 < K; k0 += 8) {
        float4 av = *(const float4*)(Aptr + k0);                 // M%128==0, K%8==0
        float4 bv = make_float4(0.f, 0.f, 0.f, 0.f);
        if (bn + bcol + 4 <= N)
            bv = *(const float4*)(B + (size_t)(k0 + brow) * ldb + bn + bcol);

        __syncthreads();   // previous iteration's compute done
        As[acol + 0][arow] = av.x;
        As[acol + 1][arow] = av.y;
        As[acol + 2][arow] = av.z;
        As[acol + 3][arow] = av.w;
        *(float4*)&Bs[brow][bcol] = bv;
        __syncthreads();

#pragma unroll
        for (int kk = 0; kk < 8; ++kk) {
            float a[8], b[8];
#pragma unroll
            for (int i = 0; i < 8; ++i) a[i] = As[kk][ty * 8 + i];
            float4 b0 = *(const float4*)&Bs[kk][4 * tx];        // bank-group = tx&7
            float4 b1 = *(const float4*)&Bs[kk][64 + 4 * tx];
            b[0] = b0.x; b[1] = b0.y; b[2] = b0.z; b[3] = b0.w;
            b[4] = b1.x; b[5] = b1.y; b[6] = b1.z; b[7] = b1.w;
#pragma unroll
            for (int i = 0; i < 8; ++i)
#pragma unroll
                for (int j = 0; j < 8; ++j)
                    acc[i][j] += a[i] * b[j];
        }
    }

    // C cols: {bn+4*tx+0..3, bn+64+4*tx+0..3}
#pragma unroll
    for (int i = 0; i < 8; ++i) {
        const int row = bm + ty * 8 + i;
        float* crow = C + (size_t)row * ldc;
        const int c0 = bn + 4 * tx;
        const int c1 = bn + 64 + 4 * tx;
        if (c0 + 4 <= N) {
            float4 v = make_float4(acc[i][0], acc[i][1], acc[i][2], acc[i][3]);
            *(float4*)(crow + c0) = v;
        }
        if (c1 + 4 <= N) {
            float4 v = make_float4(acc[i][4], acc[i][5], acc[i][6], acc[i][7]);
            *(float4*)(crow + c1) = v;
        }
    }
}

// ---------------------------------------------------------------------------
// In-place RMSNorm over the first `len` columns of each `stride`-wide row.
// ---------------------------------------------------------------------------
__global__ __launch_bounds__(256) void rmsnorm_k(
    float* __restrict__ x, const float* __restrict__ g, int len, int stride)
{
    float* xr = x + (size_t)blockIdx.x * stride;
    float ss = 0.f;
    for (int i = threadIdx.x; i < len; i += 256) {
        float v = xr[i];
        ss += v * v;
    }
#pragma unroll
    for (int off = 32; off > 0; off >>= 1) ss += __shfl_down(ss, off);
    __shared__ float red[4];
    if ((threadIdx.x & 63) == 0) red[threadIdx.x >> 6] = ss;
    __syncthreads();
    float tot = red[0] + red[1] + red[2] + red[3];
    float scale = rsqrtf(tot / (float)len + 1e-6f);
    for (int i = threadIdx.x; i < len; i += 256) xr[i] = xr[i] * scale * g[i];
}

// ---------------------------------------------------------------------------
// RoPE (GPT-J interleaved rotate, NEOX concatenated cos/sin)
// ---------------------------------------------------------------------------
#define ROPE_LN_THETA_OVER_32 0.28782313662425575f  // ln(10000)/32

__device__ __forceinline__ void rope_pair(float p, int i, float& x0, float& x1)
{
    const int   j0 = (2 * i) & 31;
    const int   j1 = (2 * i + 1) & 31;
    const float a0 = p * expf(-(float)j0 * ROPE_LN_THETA_OVER_32);
    const float a1 = p * expf(-(float)j1 * ROPE_LN_THETA_OVER_32);
    const float r0 = x0 * cosf(a0) - x1 * sinf(a0);
    const float r1 = x1 * cosf(a1) + x0 * sinf(a1);
    x0 = r0; x1 = r1;
}

__global__ __launch_bounds__(256) void rope_q_k(
    float* __restrict__ q, const int* __restrict__ pos)
{
    const int idx = blockIdx.x * 256 + threadIdx.x;  // t*1024 + h*32 + i
    const int i = idx & 31;
    const int h = (idx >> 5) & 31;
    const int t = idx >> 10;
    float* base = q + (size_t)t * QROW + h * QD + DQ;
    float x0 = base[2 * i], x1 = base[2 * i + 1];
    rope_pair((float)pos[t], i, x0, x1);
    base[2 * i] = x0;
    base[2 * i + 1] = x1;
}

__global__ __launch_bounds__(256) void rope_k_k(
    float* __restrict__ kv, const int* __restrict__ pos)
{
    const int idx = blockIdx.x * 256 + threadIdx.x;  // t*32 + i
    const int i = idx & 31;
    const int t = idx >> 5;
    float* base = kv + (size_t)t * KVD + KV_LORA;
    float x0 = base[2 * i], x1 = base[2 * i + 1];
    rope_pair((float)pos[t], i, x0, x1);
    base[2 * i] = x0;
    base[2 * i + 1] = x1;
}

// ---------------------------------------------------------------------------
// Flash-style causal attention, bank-conflict-free LDS layout.
//
// Q/K tiles stored XOR-swizzled at float4 granularity:
//   logical (row r, float4-group c in 0..47) -> phys group (c&~7)|((c^r)&7)
//   bank-group of a b128 read = (c^r)&7.
// Thread t: q-row qr=t>>3, lane-group kg=t&7.
//   Scores: keys {kg, 8+kg, 16+kg, 24+kg} (row&7 = kg -> 8 distinct
//   bank-groups per phase).  V dims: float4 groups {kg, kg+8, kg+16, kg+24}
//   (bank-group = kg).  Ps row stride 36 -> distinct banks for all 64 lanes.
// ---------------------------------------------------------------------------
__global__ __launch_bounds__(256) void attn_k(
    const float* __restrict__ q, const float* __restrict__ kvup,
    const float* __restrict__ kv, float* __restrict__ out)
{
    const int h  = blockIdx.x;
    const int qb = blockIdx.y;
    const int q0 = qb * 32;

    __shared__ float Qs[32 * 192];   // swizzled
    __shared__ float Ks[32 * 192];   // swizzled
    __shared__ float Vs[32 * 128];   // plain row-major
    __shared__ float Ps[32 * 36];
    __shared__ float redm[32][8];
    __shared__ float reds[32][8];

    const int tid = threadIdx.x;
    const int qr  = tid >> 3;        // 0..31
    const int kg  = tid & 7;         // 0..7

    const float scale = 0.07216878364870322f;  // (DQ+DR)^-0.5

    // Q tile -> LDS (swizzled, pre-scaled)
    for (int chunk = tid; chunk < 32 * 48; chunk += 256) {
        const int r = chunk / 48, c = chunk % 48;
        float4 v = *(const float4*)&q[(size_t)(q0 + r) * QROW + h * QD + 4 * c];
        v.x *= scale; v.y *= scale; v.z *= scale; v.w *= scale;
        const int sc = (c & ~7) | ((c ^ r) & 7);
        *(float4*)&Qs[r * 192 + 4 * sc] = v;
    }

    float m_run = -1e30f, l_run = 0.f;
    float acc[16] = {};

    for (int kt = 0; kt <= qb; ++kt) {
        __syncthreads();  // previous tile's readers done (also covers Qs store)

        // K tile (k_nope from kvup, k_pe from kv) -> LDS swizzled
        for (int chunk = tid; chunk < 32 * 48; chunk += 256) {
            const int r = chunk / 48, c = chunk % 48;
            const int k = kt * 32 + r;
            float4 v;
            if (c < 32)
                v = *(const float4*)&kvup[(size_t)k * KVUPROW + h * (DQ + DV) + 4 * c];
            else
                v = *(const float4*)&kv[(size_t)k * KVD + KV_LORA + 4 * (c - 32)];
            const int sc = (c & ~7) | ((c ^ r) & 7);
            *(float4*)&Ks[r * 192 + 4 * sc] = v;
        }
        // V tile -> LDS
        for (int chunk = tid; chunk < 32 * 32; chunk += 256) {
            const int r = chunk >> 5, c = chunk & 31;
            float4 v = *(const float4*)&kvup[(size_t)(kt * 32 + r) * KVUPROW
                                             + h * (DQ + DV) + 128 + 4 * c];
            *(float4*)&Vs[r * 128 + 4 * c] = v;
        }
        __syncthreads();

        // Scores: 4 keys per thread, strided by 8
        float s[4] = {0.f, 0.f, 0.f, 0.f};
        for (int c = 0; c < 48; ++c) {
            const int qg = (c & ~7) | ((c ^ qr) & 7);
            const int kgrp = (c & ~7) | ((c ^ kg) & 7);   // k&7 == kg for all 4 keys
            float4 qv = *(const float4*)&Qs[qr * 192 + 4 * qg];
#pragma unroll
            for (int jj = 0; jj < 4; ++jj) {
                float4 kvv = *(const float4*)&Ks[(8 * jj + kg) * 192 + 4 * kgrp];
                s[jj] += qv.x * kvv.x + qv.y * kvv.y + qv.z * kvv.z + qv.w * kvv.w;
            }
        }

        bool valid[4];
        float tmax = -1e30f;
#pragma unroll
        for (int jj = 0; jj < 4; ++jj) {
            valid[jj] = (kt * 32 + 8 * jj + kg) <= (q0 + qr);
            if (!valid[jj]) s[jj] = -1e30f;
            tmax = fmaxf(tmax, s[jj]);
        }
        redm[qr][kg] = tmax;
        __syncthreads();

        float tile_max = redm[qr][0];
#pragma unroll
        for (int w = 1; w < 8; ++w) tile_max = fmaxf(tile_max, redm[qr][w]);
        const float new_m = fmaxf(m_run, tile_max);
        const float alpha = expf(m_run - new_m);

        float psum = 0.f;
#pragma unroll
        for (int jj = 0; jj < 4; ++jj) {
            float pv = valid[jj] ? expf(s[jj] - new_m) : 0.f;
            Ps[qr * 36 + 8 * jj + kg] = pv;
            psum += pv;
        }
        reds[qr][kg] = psum;
        __syncthreads();

        float sum8 = 0.f;
#pragma unroll
        for (int w = 0; w < 8; ++w) sum8 += reds[qr][w];
        l_run = l_run * alpha + sum8;
        m_run = new_m;

#pragma unroll
        for (int j = 0; j < 16; ++j) acc[j] *= alpha;
        for (int kk = 0; kk < 32; ++kk) {
            const float pv = Ps[qr * 36 + kk];
#pragma unroll
            for (int j4 = 0; j4 < 4; ++j4) {
                // V float4 group kg + 8*j4 -> bank-group kg (conflict-free)
                float4 vv = *(const float4*)&Vs[kk * 128 + 4 * (kg + 8 * j4)];
                acc[j4 * 4 + 0] += pv * vv.x;
                acc[j4 * 4 + 1] += pv * vv.y;
                acc[j4 * 4 + 2] += pv * vv.z;
                acc[j4 * 4 + 3] += pv * vv.w;
            }
        }
    }

    const float inv_l = 1.f / l_run;
    float* op = out + (size_t)(q0 + qr) * AOROW + h * DV;
#pragma unroll
    for (int j4 = 0; j4 < 4; ++j4) {
        float4 v = make_float4(acc[j4 * 4 + 0] * inv_l, acc[j4 * 4 + 1] * inv_l,
                               acc[j4 * 4 + 2] * inv_l, acc[j4 * 4 + 3] * inv_l);
        *(float4*)(op + 4 * (kg + 8 * j4)) = v;   // lanes kg=0..7: 32 consecutive floats
    }
}

// ---------------------------------------------------------------------------
extern "C" void kernel_launch(void* const* d_in, const int* in_sizes, int n_in,
                              void* d_out, int out_size, void* d_ws, size_t ws_size,
                              hipStream_t stream)
{
    const int*   positions = (const int*)d_in[0];
    const float* hidden    = (const float*)d_in[1];
    const float* w_qa      = (const float*)d_in[2];
    const float* gamma_q   = (const float*)d_in[3];
    const float* w_qb      = (const float*)d_in[4];
    const float* w_kva     = (const float*)d_in[5];
    const float* gamma_kv  = (const float*)d_in[6];
    const float* w_kvb     = (const float*)d_in[7];
    const float* w_o       = (const float*)d_in[8];
    float*       out       = (float*)d_out;

    // Workspace layout (fp32): total ~168.3 MB
    float* qa   = (float*)d_ws;                       // [2048,1536]
    float* qbuf = qa   + (size_t)T_SEQ * Q_LORA;      // [2048,6144]
    float* kvb  = qbuf + (size_t)T_SEQ * QROW;        // [2048,576]
    float* kvup = kvb  + (size_t)T_SEQ * KVD;         // [2048,8192]
    float* aout = kvup + (size_t)T_SEQ * KVUPROW;     // [2048,4096]

    const dim3 blk(256);

    // 1) qa = hidden @ w_qa
    gemm_f32<<<dim3(Q_LORA / 128, T_SEQ / 128), blk, 0, stream>>>(
        hidden, w_qa, qa, T_SEQ, Q_LORA, HIDDEN, HIDDEN, Q_LORA, Q_LORA);
    // 2) rmsnorm(qa) in place
    rmsnorm_k<<<dim3(T_SEQ), blk, 0, stream>>>(qa, gamma_q, Q_LORA, Q_LORA);
    // 3) qbuf = qa @ w_qb
    gemm_f32<<<dim3(QROW / 128, T_SEQ / 128), blk, 0, stream>>>(
        qa, w_qb, qbuf, T_SEQ, QROW, Q_LORA, Q_LORA, QROW, QROW);
    // 4) kvb = hidden @ w_kva   (N=576 -> guarded tiles)
    gemm_f32<<<dim3((KVD + 127) / 128, T_SEQ / 128), blk, 0, stream>>>(
        hidden, w_kva, kvb, T_SEQ, KVD, HIDDEN, HIDDEN, KVD, KVD);
    // 5) rmsnorm on kvb[:, :512] in place (row stride 576)
    rmsnorm_k<<<dim3(T_SEQ), blk, 0, stream>>>(kvb, gamma_kv, KV_LORA, KVD);
    // 6) RoPE on k_pe (kvb cols 512..575), in place
    rope_k_k<<<dim3(T_SEQ * 32 / 256), blk, 0, stream>>>(kvb, positions);
    // 7) kvup = kv_c @ w_kvb  (A = kvb with lda=576, K=512)
    gemm_f32<<<dim3(KVUPROW / 128, T_SEQ / 128), blk, 0, stream>>>(
        kvb, w_kvb, kvup, T_SEQ, KVUPROW, KV_LORA, KVD, KVUPROW, KVUPROW);
    // 8) RoPE on q_pe (qbuf cols 128..191 of each head), in place
    rope_q_k<<<dim3(T_SEQ * NH * 32 / 256), blk, 0, stream>>>(qbuf, positions);
    // 9) causal flash attention -> aout [2048, 4096]
    attn_k<<<dim3(NH, T_SEQ / 32), blk, 0, stream>>>(qbuf, kvup, kvb, aout);
    // 10) out = aout @ w_o
    gemm_f32<<<dim3(HIDDEN / 128, T_SEQ / 128), blk, 0, stream>>>(
        aout, w_o, out, T_SEQ, HIDDEN, AOROW, AOROW, HIDDEN, HIDDEN);
}

// Round 3
// 3250.066 us; speedup vs baseline: 2.6096x; 1.6956x over previous
//
#include <hip/hip_runtime.h>
#include <hip/hip_bf16.h>
#include <cstdint>
#include <cstddef>

#define T_SEQ   2048
#define HIDDEN  5120
#define NH      32
#define DQ      128
#define DR      64
#define DV      128
#define Q_LORA  1536
#define KV_LORA 512
#define QD      (DQ + DR)          // 192
#define KVD     (KV_LORA + DR)     // 576
#define QROW    (NH * QD)          // 6144
#define KVUPROW (NH * (DQ + DV))   // 8192
#define AOROW   (NH * DV)          // 4096

typedef short bf16x8 __attribute__((ext_vector_type(8)));   // 8 bf16 raw (4 VGPRs)
typedef float f32x4  __attribute__((ext_vector_type(4)));

// fp32 -> bf16 raw bits, round-to-nearest-even (inputs are finite/sane)
static __device__ __forceinline__ short f2bf(float f)
{
    union { float f; unsigned u; } v; v.f = f;
    unsigned r = v.u + 0x7FFFu + ((v.u >> 16) & 1u);
    return (short)(r >> 16);
}

// ---------------------------------------------------------------------------
// bf16 MFMA GEMM: C[M,N](f32) = A[M,K](f32) @ B[K,N](f32), inputs converted
// to bf16 during LDS staging, fp32 accumulate in MFMA.
// 128x128 block tile, BK=32, 256 threads = 4 waves (2x2 of 64x64 each),
// 4x4 of 16x16x32 MFMA tiles per wave.
// LDS: As[128][40] bf16 row-major (m,k); Bs[128][40] bf16 as B^T (n,k) so
// both fragments are single ds_read_b128 (pad 40 keeps phases ~2-way).
// M %128, K %32 required (true for all five calls); N guarded (N=576).
// ---------------------------------------------------------------------------
__global__ __launch_bounds__(256) void gemm_bf16(
    const float* __restrict__ A, const float* __restrict__ B,
    float* __restrict__ C, int N, int K, int lda, int ldb, int ldc)
{
    __shared__ short As[128 * 40];
    __shared__ short Bs[128 * 40];

    const int tid  = threadIdx.x;
    const int bm   = blockIdx.y * 128;
    const int bn   = blockIdx.x * 128;
    const int w    = tid >> 6;
    const int l    = tid & 63;
    const int wm   = (w >> 1) * 64;
    const int wn   = (w & 1) * 64;
    const int quad = l >> 4;
    const int lrow = l & 15;

    f32x4 acc[4][4];
#pragma unroll
    for (int mt = 0; mt < 4; ++mt)
#pragma unroll
        for (int nt = 0; nt < 4; ++nt)
            acc[mt][nt] = (f32x4){0.f, 0.f, 0.f, 0.f};

    for (int k0 = 0; k0 < K; k0 += 32) {
        // Global loads first (latency overlap with the barrier)
        float4 av[4], bv[4];
#pragma unroll
        for (int i = 0; i < 4; ++i) {                 // A tile 128x32
            const int f = tid + 256 * i;
            const int r = f >> 3, c = (f & 7) * 4;
            av[i] = *(const float4*)(A + (size_t)(bm + r) * lda + k0 + c);
        }
#pragma unroll
        for (int i = 0; i < 4; ++i) {                 // B tile 32x128 (guarded)
            const int f = tid + 256 * i;
            const int kk = f >> 5, n = (f & 31) * 4;
            bv[i] = make_float4(0.f, 0.f, 0.f, 0.f);
            if (bn + n + 4 <= N)
                bv[i] = *(const float4*)(B + (size_t)(k0 + kk) * ldb + bn + n);
        }

        __syncthreads();   // previous iteration's fragment reads done
#pragma unroll
        for (int i = 0; i < 4; ++i) {
            const int f = tid + 256 * i;
            const int r = f >> 3, c = (f & 7) * 4;
            union { short s[4]; uint2 u; } t;
            t.s[0] = f2bf(av[i].x); t.s[1] = f2bf(av[i].y);
            t.s[2] = f2bf(av[i].z); t.s[3] = f2bf(av[i].w);
            *(uint2*)&As[r * 40 + c] = t.u;           // 8B aligned
        }
#pragma unroll
        for (int i = 0; i < 4; ++i) {                 // transpose into Bs[n][k]
            const int f = tid + 256 * i;
            const int kk = f >> 5, n = (f & 31) * 4;
            Bs[(n + 0) * 40 + kk] = f2bf(bv[i].x);
            Bs[(n + 1) * 40 + kk] = f2bf(bv[i].y);
            Bs[(n + 2) * 40 + kk] = f2bf(bv[i].z);
            Bs[(n + 3) * 40 + kk] = f2bf(bv[i].w);
        }
        __syncthreads();

        bf16x8 af[4], bfr[4];
#pragma unroll
        for (int mt = 0; mt < 4; ++mt)   // A[m=lane&15][k=quad*8+j]
            af[mt] = *(const bf16x8*)&As[(wm + mt * 16 + lrow) * 40 + quad * 8];
#pragma unroll
        for (int nt = 0; nt < 4; ++nt)   // B[k=quad*8+j][n=lane&15] via B^T rows
            bfr[nt] = *(const bf16x8*)&Bs[(wn + nt * 16 + lrow) * 40 + quad * 8];
#pragma unroll
        for (int mt = 0; mt < 4; ++mt)
#pragma unroll
            for (int nt = 0; nt < 4; ++nt)
                acc[mt][nt] = __builtin_amdgcn_mfma_f32_16x16x32_bf16(
                    af[mt], bfr[nt], acc[mt][nt], 0, 0, 0);
    }

    // C/D layout: col = lane&15, row = quad*4 + i  (m89-verified)
#pragma unroll
    for (int mt = 0; mt < 4; ++mt) {
#pragma unroll
        for (int i = 0; i < 4; ++i) {
            const int row = bm + wm + mt * 16 + quad * 4 + i;
            float* crow = C + (size_t)row * ldc;
#pragma unroll
            for (int nt = 0; nt < 4; ++nt) {
                const int col = bn + wn + nt * 16 + lrow;
                if (col < N) crow[col] = acc[mt][nt][i];
            }
        }
    }
}

// ---------------------------------------------------------------------------
// In-place RMSNorm over the first `len` columns of each `stride`-wide row.
// ---------------------------------------------------------------------------
__global__ __launch_bounds__(256) void rmsnorm_k(
    float* __restrict__ x, const float* __restrict__ g, int len, int stride)
{
    float* xr = x + (size_t)blockIdx.x * stride;
    float ss = 0.f;
    for (int i = threadIdx.x; i < len; i += 256) {
        float v = xr[i];
        ss += v * v;
    }
#pragma unroll
    for (int off = 32; off > 0; off >>= 1) ss += __shfl_down(ss, off);
    __shared__ float red[4];
    if ((threadIdx.x & 63) == 0) red[threadIdx.x >> 6] = ss;
    __syncthreads();
    float tot = red[0] + red[1] + red[2] + red[3];
    float scale = rsqrtf(tot / (float)len + 1e-6f);
    for (int i = threadIdx.x; i < len; i += 256) xr[i] = xr[i] * scale * g[i];
}

// ---------------------------------------------------------------------------
// RoPE (GPT-J interleaved rotate, NEOX concatenated cos/sin)
// ---------------------------------------------------------------------------
#define ROPE_LN_THETA_OVER_32 0.28782313662425575f  // ln(10000)/32

__device__ __forceinline__ void rope_pair(float p, int i, float& x0, float& x1)
{
    const int   j0 = (2 * i) & 31;
    const int   j1 = (2 * i + 1) & 31;
    const float a0 = p * expf(-(float)j0 * ROPE_LN_THETA_OVER_32);
    const float a1 = p * expf(-(float)j1 * ROPE_LN_THETA_OVER_32);
    const float r0 = x0 * cosf(a0) - x1 * sinf(a0);
    const float r1 = x1 * cosf(a1) + x0 * sinf(a1);
    x0 = r0; x1 = r1;
}

__global__ __launch_bounds__(256) void rope_q_k(
    float* __restrict__ q, const int* __restrict__ pos)
{
    const int idx = blockIdx.x * 256 + threadIdx.x;  // t*1024 + h*32 + i
    const int i = idx & 31;
    const int h = (idx >> 5) & 31;
    const int t = idx >> 10;
    float* base = q + (size_t)t * QROW + h * QD + DQ;
    float x0 = base[2 * i], x1 = base[2 * i + 1];
    rope_pair((float)pos[t], i, x0, x1);
    base[2 * i] = x0;
    base[2 * i + 1] = x1;
}

__global__ __launch_bounds__(256) void rope_k_k(
    float* __restrict__ kv, const int* __restrict__ pos)
{
    const int idx = blockIdx.x * 256 + threadIdx.x;  // t*32 + i
    const int i = idx & 31;
    const int t = idx >> 5;
    float* base = kv + (size_t)t * KVD + KV_LORA;
    float x0 = base[2 * i], x1 = base[2 * i + 1];
    rope_pair((float)pos[t], i, x0, x1);
    base[2 * i] = x0;
    base[2 * i + 1] = x1;
}

// ---------------------------------------------------------------------------
// Flash-style causal attention, bank-conflict-free LDS layout (round-2 form).
// ---------------------------------------------------------------------------
__global__ __launch_bounds__(256) void attn_k(
    const float* __restrict__ q, const float* __restrict__ kvup,
    const float* __restrict__ kv, float* __restrict__ out)
{
    const int h  = blockIdx.x;
    const int qb = blockIdx.y;
    const int q0 = qb * 32;

    __shared__ float Qs[32 * 192];   // swizzled
    __shared__ float Ks[32 * 192];   // swizzled
    __shared__ float Vs[32 * 128];   // plain row-major
    __shared__ float Ps[32 * 36];
    __shared__ float redm[32][8];
    __shared__ float reds[32][8];

    const int tid = threadIdx.x;
    const int qr  = tid >> 3;        // 0..31
    const int kg  = tid & 7;         // 0..7

    const float scale = 0.07216878364870322f;  // (DQ+DR)^-0.5

    for (int chunk = tid; chunk < 32 * 48; chunk += 256) {
        const int r = chunk / 48, c = chunk % 48;
        float4 v = *(const float4*)&q[(size_t)(q0 + r) * QROW + h * QD + 4 * c];
        v.x *= scale; v.y *= scale; v.z *= scale; v.w *= scale;
        const int sc = (c & ~7) | ((c ^ r) & 7);
        *(float4*)&Qs[r * 192 + 4 * sc] = v;
    }

    float m_run = -1e30f, l_run = 0.f;
    float acc[16] = {};

    for (int kt = 0; kt <= qb; ++kt) {
        __syncthreads();

        for (int chunk = tid; chunk < 32 * 48; chunk += 256) {
            const int r = chunk / 48, c = chunk % 48;
            const int k = kt * 32 + r;
            float4 v;
            if (c < 32)
                v = *(const float4*)&kvup[(size_t)k * KVUPROW + h * (DQ + DV) + 4 * c];
            else
                v = *(const float4*)&kv[(size_t)k * KVD + KV_LORA + 4 * (c - 32)];
            const int sc = (c & ~7) | ((c ^ r) & 7);
            *(float4*)&Ks[r * 192 + 4 * sc] = v;
        }
        for (int chunk = tid; chunk < 32 * 32; chunk += 256) {
            const int r = chunk >> 5, c = chunk & 31;
            float4 v = *(const float4*)&kvup[(size_t)(kt * 32 + r) * KVUPROW
                                             + h * (DQ + DV) + 128 + 4 * c];
            *(float4*)&Vs[r * 128 + 4 * c] = v;
        }
        __syncthreads();

        float s[4] = {0.f, 0.f, 0.f, 0.f};
        for (int c = 0; c < 48; ++c) {
            const int qg = (c & ~7) | ((c ^ qr) & 7);
            const int kgrp = (c & ~7) | ((c ^ kg) & 7);
            float4 qv = *(const float4*)&Qs[qr * 192 + 4 * qg];
#pragma unroll
            for (int jj = 0; jj < 4; ++jj) {
                float4 kvv = *(const float4*)&Ks[(8 * jj + kg) * 192 + 4 * kgrp];
                s[jj] += qv.x * kvv.x + qv.y * kvv.y + qv.z * kvv.z + qv.w * kvv.w;
            }
        }

        bool valid[4];
        float tmax = -1e30f;
#pragma unroll
        for (int jj = 0; jj < 4; ++jj) {
            valid[jj] = (kt * 32 + 8 * jj + kg) <= (q0 + qr);
            if (!valid[jj]) s[jj] = -1e30f;
            tmax = fmaxf(tmax, s[jj]);
        }
        redm[qr][kg] = tmax;
        __syncthreads();

        float tile_max = redm[qr][0];
#pragma unroll
        for (int w = 1; w < 8; ++w) tile_max = fmaxf(tile_max, redm[qr][w]);
        const float new_m = fmaxf(m_run, tile_max);
        const float alpha = expf(m_run - new_m);

        float psum = 0.f;
#pragma unroll
        for (int jj = 0; jj < 4; ++jj) {
            float pv = valid[jj] ? expf(s[jj] - new_m) : 0.f;
            Ps[qr * 36 + 8 * jj + kg] = pv;
            psum += pv;
        }
        reds[qr][kg] = psum;
        __syncthreads();

        float sum8 = 0.f;
#pragma unroll
        for (int w = 0; w < 8; ++w) sum8 += reds[qr][w];
        l_run = l_run * alpha + sum8;
        m_run = new_m;

#pragma unroll
        for (int j = 0; j < 16; ++j) acc[j] *= alpha;
        for (int kk = 0; kk < 32; ++kk) {
            const float pv = Ps[qr * 36 + kk];
#pragma unroll
            for (int j4 = 0; j4 < 4; ++j4) {
                float4 vv = *(const float4*)&Vs[kk * 128 + 4 * (kg + 8 * j4)];
                acc[j4 * 4 + 0] += pv * vv.x;
                acc[j4 * 4 + 1] += pv * vv.y;
                acc[j4 * 4 + 2] += pv * vv.z;
                acc[j4 * 4 + 3] += pv * vv.w;
            }
        }
    }

    const float inv_l = 1.f / l_run;
    float* op = out + (size_t)(q0 + qr) * AOROW + h * DV;
#pragma unroll
    for (int j4 = 0; j4 < 4; ++j4) {
        float4 v = make_float4(acc[j4 * 4 + 0] * inv_l, acc[j4 * 4 + 1] * inv_l,
                               acc[j4 * 4 + 2] * inv_l, acc[j4 * 4 + 3] * inv_l);
        *(float4*)(op + 4 * (kg + 8 * j4)) = v;
    }
}

// ---------------------------------------------------------------------------
extern "C" void kernel_launch(void* const* d_in, const int* in_sizes, int n_in,
                              void* d_out, int out_size, void* d_ws, size_t ws_size,
                              hipStream_t stream)
{
    const int*   positions = (const int*)d_in[0];
    const float* hidden    = (const float*)d_in[1];
    const float* w_qa      = (const float*)d_in[2];
    const float* gamma_q   = (const float*)d_in[3];
    const float* w_qb      = (const float*)d_in[4];
    const float* w_kva     = (const float*)d_in[5];
    const float* gamma_kv  = (const float*)d_in[6];
    const float* w_kvb     = (const float*)d_in[7];
    const float* w_o       = (const float*)d_in[8];
    float*       out       = (float*)d_out;

    // Workspace layout (fp32): total ~168.3 MB
    float* qa   = (float*)d_ws;                       // [2048,1536]
    float* qbuf = qa   + (size_t)T_SEQ * Q_LORA;      // [2048,6144]
    float* kvb  = qbuf + (size_t)T_SEQ * QROW;        // [2048,576]
    float* kvup = kvb  + (size_t)T_SEQ * KVD;         // [2048,8192]
    float* aout = kvup + (size_t)T_SEQ * KVUPROW;     // [2048,4096]

    const dim3 blk(256);

    // 1) qa = hidden @ w_qa
    gemm_bf16<<<dim3(Q_LORA / 128, T_SEQ / 128), blk, 0, stream>>>(
        hidden, w_qa, qa, Q_LORA, HIDDEN, HIDDEN, Q_LORA, Q_LORA);
    // 2) rmsnorm(qa) in place
    rmsnorm_k<<<dim3(T_SEQ), blk, 0, stream>>>(qa, gamma_q, Q_LORA, Q_LORA);
    // 3) qbuf = qa @ w_qb
    gemm_bf16<<<dim3(QROW / 128, T_SEQ / 128), blk, 0, stream>>>(
        qa, w_qb, qbuf, QROW, Q_LORA, Q_LORA, QROW, QROW);
    // 4) kvb = hidden @ w_kva   (N=576 -> guarded tiles)
    gemm_bf16<<<dim3((KVD + 127) / 128, T_SEQ / 128), blk, 0, stream>>>(
        hidden, w_kva, kvb, KVD, HIDDEN, HIDDEN, KVD, KVD);
    // 5) rmsnorm on kvb[:, :512] in place (row stride 576)
    rmsnorm_k<<<dim3(T_SEQ), blk, 0, stream>>>(kvb, gamma_kv, KV_LORA, KVD);
    // 6) RoPE on k_pe (kvb cols 512..575), in place
    rope_k_k<<<dim3(T_SEQ * 32 / 256), blk, 0, stream>>>(kvb, positions);
    // 7) kvup = kv_c @ w_kvb  (A = kvb with lda=576, K=512)
    gemm_bf16<<<dim3(KVUPROW / 128, T_SEQ / 128), blk, 0, stream>>>(
        kvb, w_kvb, kvup, KVUPROW, KV_LORA, KVD, KVUPROW, KVUPROW);
    // 8) RoPE on q_pe (qbuf cols 128..191 of each head), in place
    rope_q_k<<<dim3(T_SEQ * NH * 32 / 256), blk, 0, stream>>>(qbuf, positions);
    // 9) causal flash attention -> aout [2048, 4096]
    attn_k<<<dim3(NH, T_SEQ / 32), blk, 0, stream>>>(qbuf, kvup, kvb, aout);
    // 10) out = aout @ w_o
    gemm_bf16<<<dim3(HIDDEN / 128, T_SEQ / 128), blk, 0, stream>>>(
        aout, w_o, out, HIDDEN, AOROW, AOROW, HIDDEN, HIDDEN);
}

// Round 4
// 1707.662 us; speedup vs baseline: 4.9667x; 1.9032x over previous
//
#include <hip/hip_runtime.h>
#include <hip/hip_bf16.h>
#include <cstdint>
#include <cstddef>

#define T_SEQ   2048
#define HIDDEN  5120
#define NH      32
#define DQ      128
#define DR      64
#define DV      128
#define Q_LORA  1536
#define KV_LORA 512
#define QD      (DQ + DR)          // 192
#define KVD     (KV_LORA + DR)     // 576
#define QROW    (NH * QD)          // 6144
#define KVUPROW (NH * (DQ + DV))   // 8192
#define AOROW   (NH * DV)          // 4096

typedef short bf16x8 __attribute__((ext_vector_type(8)));   // 8 bf16 raw (4 VGPRs)
typedef float f32x4  __attribute__((ext_vector_type(4)));

// fp32 -> bf16 raw bits, round-to-nearest-even
static __device__ __forceinline__ short f2bf(float f)
{
    union { float f; unsigned u; } v; v.f = f;
    unsigned r = v.u + 0x7FFFu + ((v.u >> 16) & 1u);
    return (short)(r >> 16);
}

// ---------------------------------------------------------------------------
// bf16 MFMA GEMM: C[M,N](f32) = A[M,K](f32) @ B[K,N](f32).
// 128x128 tile, BK=32, 4 waves 2x2, 4x4 16x16x32 MFMA tiles/wave. (round-3)
// ---------------------------------------------------------------------------
__global__ __launch_bounds__(256) void gemm_bf16(
    const float* __restrict__ A, const float* __restrict__ B,
    float* __restrict__ C, int N, int K, int lda, int ldb, int ldc)
{
    __shared__ short As[128 * 40];
    __shared__ short Bs[128 * 40];

    const int tid  = threadIdx.x;
    const int bm   = blockIdx.y * 128;
    const int bn   = blockIdx.x * 128;
    const int w    = tid >> 6;
    const int l    = tid & 63;
    const int wm   = (w >> 1) * 64;
    const int wn   = (w & 1) * 64;
    const int quad = l >> 4;
    const int lrow = l & 15;

    f32x4 acc[4][4];
#pragma unroll
    for (int mt = 0; mt < 4; ++mt)
#pragma unroll
        for (int nt = 0; nt < 4; ++nt)
            acc[mt][nt] = (f32x4){0.f, 0.f, 0.f, 0.f};

    for (int k0 = 0; k0 < K; k0 += 32) {
        float4 av[4], bv[4];
#pragma unroll
        for (int i = 0; i < 4; ++i) {
            const int f = tid + 256 * i;
            const int r = f >> 3, c = (f & 7) * 4;
            av[i] = *(const float4*)(A + (size_t)(bm + r) * lda + k0 + c);
        }
#pragma unroll
        for (int i = 0; i < 4; ++i) {
            const int f = tid + 256 * i;
            const int kk = f >> 5, n = (f & 31) * 4;
            bv[i] = make_float4(0.f, 0.f, 0.f, 0.f);
            if (bn + n + 4 <= N)
                bv[i] = *(const float4*)(B + (size_t)(k0 + kk) * ldb + bn + n);
        }

        __syncthreads();
#pragma unroll
        for (int i = 0; i < 4; ++i) {
            const int f = tid + 256 * i;
            const int r = f >> 3, c = (f & 7) * 4;
            union { short s[4]; uint2 u; } t;
            t.s[0] = f2bf(av[i].x); t.s[1] = f2bf(av[i].y);
            t.s[2] = f2bf(av[i].z); t.s[3] = f2bf(av[i].w);
            *(uint2*)&As[r * 40 + c] = t.u;
        }
#pragma unroll
        for (int i = 0; i < 4; ++i) {
            const int f = tid + 256 * i;
            const int kk = f >> 5, n = (f & 31) * 4;
            Bs[(n + 0) * 40 + kk] = f2bf(bv[i].x);
            Bs[(n + 1) * 40 + kk] = f2bf(bv[i].y);
            Bs[(n + 2) * 40 + kk] = f2bf(bv[i].z);
            Bs[(n + 3) * 40 + kk] = f2bf(bv[i].w);
        }
        __syncthreads();

        bf16x8 af[4], bfr[4];
#pragma unroll
        for (int mt = 0; mt < 4; ++mt)
            af[mt] = *(const bf16x8*)&As[(wm + mt * 16 + lrow) * 40 + quad * 8];
#pragma unroll
        for (int nt = 0; nt < 4; ++nt)
            bfr[nt] = *(const bf16x8*)&Bs[(wn + nt * 16 + lrow) * 40 + quad * 8];
#pragma unroll
        for (int mt = 0; mt < 4; ++mt)
#pragma unroll
            for (int nt = 0; nt < 4; ++nt)
                acc[mt][nt] = __builtin_amdgcn_mfma_f32_16x16x32_bf16(
                    af[mt], bfr[nt], acc[mt][nt], 0, 0, 0);
    }

#pragma unroll
    for (int mt = 0; mt < 4; ++mt) {
#pragma unroll
        for (int i = 0; i < 4; ++i) {
            const int row = bm + wm + mt * 16 + quad * 4 + i;
            float* crow = C + (size_t)row * ldc;
#pragma unroll
            for (int nt = 0; nt < 4; ++nt) {
                const int col = bn + wn + nt * 16 + lrow;
                if (col < N) crow[col] = acc[mt][nt][i];
            }
        }
    }
}

// ---------------------------------------------------------------------------
// kv-up GEMM with bf16 epilogue into attention layouts:
//   cols h*256+d, d<128  -> Kg[h][row][d]      (bf16, k_nope)
//   cols h*256+128+dv    -> Vg[h][dv][row]     (bf16, transposed V)
// M=2048, N=8192, K=512. Block covers one 128-col half of one head.
// ---------------------------------------------------------------------------
__global__ __launch_bounds__(256) void gemm_kv(
    const float* __restrict__ A, const float* __restrict__ B,
    short* __restrict__ Kg, short* __restrict__ Vg, int lda, int ldb)
{
    __shared__ short As[128 * 40];
    __shared__ short Bs[128 * 40];

    const int tid  = threadIdx.x;
    const int bm   = blockIdx.y * 128;
    const int bn   = blockIdx.x * 128;
    const int w    = tid >> 6;
    const int l    = tid & 63;
    const int wm   = (w >> 1) * 64;
    const int wn   = (w & 1) * 64;
    const int quad = l >> 4;
    const int lrow = l & 15;

    f32x4 acc[4][4];
#pragma unroll
    for (int mt = 0; mt < 4; ++mt)
#pragma unroll
        for (int nt = 0; nt < 4; ++nt)
            acc[mt][nt] = (f32x4){0.f, 0.f, 0.f, 0.f};

    for (int k0 = 0; k0 < 512; k0 += 32) {
        float4 av[4], bv[4];
#pragma unroll
        for (int i = 0; i < 4; ++i) {
            const int f = tid + 256 * i;
            const int r = f >> 3, c = (f & 7) * 4;
            av[i] = *(const float4*)(A + (size_t)(bm + r) * lda + k0 + c);
        }
#pragma unroll
        for (int i = 0; i < 4; ++i) {
            const int f = tid + 256 * i;
            const int kk = f >> 5, n = (f & 31) * 4;
            bv[i] = *(const float4*)(B + (size_t)(k0 + kk) * ldb + bn + n);
        }

        __syncthreads();
#pragma unroll
        for (int i = 0; i < 4; ++i) {
            const int f = tid + 256 * i;
            const int r = f >> 3, c = (f & 7) * 4;
            union { short s[4]; uint2 u; } t;
            t.s[0] = f2bf(av[i].x); t.s[1] = f2bf(av[i].y);
            t.s[2] = f2bf(av[i].z); t.s[3] = f2bf(av[i].w);
            *(uint2*)&As[r * 40 + c] = t.u;
        }
#pragma unroll
        for (int i = 0; i < 4; ++i) {
            const int f = tid + 256 * i;
            const int kk = f >> 5, n = (f & 31) * 4;
            Bs[(n + 0) * 40 + kk] = f2bf(bv[i].x);
            Bs[(n + 1) * 40 + kk] = f2bf(bv[i].y);
            Bs[(n + 2) * 40 + kk] = f2bf(bv[i].z);
            Bs[(n + 3) * 40 + kk] = f2bf(bv[i].w);
        }
        __syncthreads();

        bf16x8 af[4], bfr[4];
#pragma unroll
        for (int mt = 0; mt < 4; ++mt)
            af[mt] = *(const bf16x8*)&As[(wm + mt * 16 + lrow) * 40 + quad * 8];
#pragma unroll
        for (int nt = 0; nt < 4; ++nt)
            bfr[nt] = *(const bf16x8*)&Bs[(wn + nt * 16 + lrow) * 40 + quad * 8];
#pragma unroll
        for (int mt = 0; mt < 4; ++mt)
#pragma unroll
            for (int nt = 0; nt < 4; ++nt)
                acc[mt][nt] = __builtin_amdgcn_mfma_f32_16x16x32_bf16(
                    af[mt], bfr[nt], acc[mt][nt], 0, 0, 0);
    }

    const int  h     = bn >> 8;
    const bool vhalf = (bn & 128) != 0;
    if (!vhalf) {
        short* KgH = Kg + (size_t)h * (2048 * 192);
#pragma unroll
        for (int mt = 0; mt < 4; ++mt)
#pragma unroll
            for (int i = 0; i < 4; ++i) {
                const int row = bm + wm + mt * 16 + quad * 4 + i;
#pragma unroll
                for (int nt = 0; nt < 4; ++nt) {
                    const int d = wn + nt * 16 + lrow;
                    KgH[(size_t)row * 192 + d] = f2bf(acc[mt][nt][i]);
                }
            }
    } else {
        short* VgH = Vg + (size_t)h * (128 * 2048);
#pragma unroll
        for (int mt = 0; mt < 4; ++mt)
#pragma unroll
            for (int nt = 0; nt < 4; ++nt) {
                const int dv   = wn + nt * 16 + lrow;
                const int rowb = bm + wm + mt * 16 + quad * 4;
                union { short s[4]; uint2 u; } t;
                t.s[0] = f2bf(acc[mt][nt][0]); t.s[1] = f2bf(acc[mt][nt][1]);
                t.s[2] = f2bf(acc[mt][nt][2]); t.s[3] = f2bf(acc[mt][nt][3]);
                *(uint2*)&VgH[(size_t)dv * 2048 + rowb] = t.u;   // 4 consecutive tokens
            }
    }
}

// ---------------------------------------------------------------------------
__global__ __launch_bounds__(256) void rmsnorm_k(
    float* __restrict__ x, const float* __restrict__ g, int len, int stride)
{
    float* xr = x + (size_t)blockIdx.x * stride;
    float ss = 0.f;
    for (int i = threadIdx.x; i < len; i += 256) {
        float v = xr[i];
        ss += v * v;
    }
#pragma unroll
    for (int off = 32; off > 0; off >>= 1) ss += __shfl_down(ss, off);
    __shared__ float red[4];
    if ((threadIdx.x & 63) == 0) red[threadIdx.x >> 6] = ss;
    __syncthreads();
    float tot = red[0] + red[1] + red[2] + red[3];
    float scale = rsqrtf(tot / (float)len + 1e-6f);
    for (int i = threadIdx.x; i < len; i += 256) xr[i] = xr[i] * scale * g[i];
}

// ---------------------------------------------------------------------------
// RoPE (GPT-J interleaved rotate, NEOX concatenated cos/sin)
// ---------------------------------------------------------------------------
#define ROPE_LN_THETA_OVER_32 0.28782313662425575f  // ln(10000)/32

__device__ __forceinline__ void rope_pair(float p, int i, float& x0, float& x1)
{
    const int   j0 = (2 * i) & 31;
    const int   j1 = (2 * i + 1) & 31;
    const float a0 = p * expf(-(float)j0 * ROPE_LN_THETA_OVER_32);
    const float a1 = p * expf(-(float)j1 * ROPE_LN_THETA_OVER_32);
    const float r0 = x0 * cosf(a0) - x1 * sinf(a0);
    const float r1 = x1 * cosf(a1) + x0 * sinf(a1);
    x0 = r0; x1 = r1;
}

__global__ __launch_bounds__(256) void rope_q_k(
    float* __restrict__ q, const int* __restrict__ pos)
{
    const int idx = blockIdx.x * 256 + threadIdx.x;  // t*1024 + h*32 + i
    const int i = idx & 31;
    const int h = (idx >> 5) & 31;
    const int t = idx >> 10;
    float* base = q + (size_t)t * QROW + h * QD + DQ;
    float x0 = base[2 * i], x1 = base[2 * i + 1];
    rope_pair((float)pos[t], i, x0, x1);
    base[2 * i] = x0;
    base[2 * i + 1] = x1;
}

// k_pe RoPE: read kvb pe cols (fp32), rotate, broadcast to all heads' Kg cols
__global__ __launch_bounds__(256) void rope_k_bcast(
    const float* __restrict__ kvb, const int* __restrict__ pos,
    short* __restrict__ Kg)
{
    const int idx = blockIdx.x * 256 + threadIdx.x;  // t*32 + i
    const int i = idx & 31;
    const int t = idx >> 5;
    const float* base = kvb + (size_t)t * KVD + KV_LORA;
    float x0 = base[2 * i], x1 = base[2 * i + 1];
    rope_pair((float)pos[t], i, x0, x1);
    union { short s[2]; unsigned u; } pk;
    pk.s[0] = f2bf(x0); pk.s[1] = f2bf(x1);
    for (int h = 0; h < NH; ++h)
        *(unsigned*)&Kg[((size_t)h * 2048 + t) * 192 + 128 + 2 * i] = pk.u;
}

// ---------------------------------------------------------------------------
// MFMA flash attention. Block = (head, 64 q-rows), 4 waves x 16 q-rows each.
// K-tiles of 64 keys. Scores: 24 MFMA/wave/tile (Q-frags hoisted). Online
// softmax via in-quad shfl_xor. P through LDS (per-wave rows, no barrier).
// PV: 16 MFMA with B-frags from transposed Vt. Padded strides -> <=2-way.
// ---------------------------------------------------------------------------
__global__ __launch_bounds__(256) void attn_mfma(
    const float* __restrict__ qbuf, const short* __restrict__ Kg,
    const short* __restrict__ Vg, float* __restrict__ aout)
{
    const int h  = blockIdx.x;
    const int qb = blockIdx.y;
    const int q0 = qb * 64;

    __shared__ short Qs[64 * 200];
    __shared__ short Ks[64 * 200];
    __shared__ short Vt[128 * 72];
    __shared__ short Ps[64 * 72];

    const int tid  = threadIdx.x;
    const int w    = tid >> 6;
    const int l    = tid & 63;
    const int quad = l >> 4;
    const int lrow = l & 15;

    const float scale = 0.07216878364870322f;  // 1/sqrt(192)

    // Q tile -> LDS bf16, pre-scaled
#pragma unroll
    for (int it = 0; it < 12; ++it) {
        const int id = tid + 256 * it;
        const int r = id / 48, c = id % 48;
        float4 v = *(const float4*)&qbuf[(size_t)(q0 + r) * QROW + h * QD + 4 * c];
        union { short s[4]; uint2 u; } t;
        t.s[0] = f2bf(v.x * scale); t.s[1] = f2bf(v.y * scale);
        t.s[2] = f2bf(v.z * scale); t.s[3] = f2bf(v.w * scale);
        *(uint2*)&Qs[r * 200 + 4 * c] = t.u;
    }
    __syncthreads();

    bf16x8 afq[6];
#pragma unroll
    for (int ks = 0; ks < 6; ++ks)
        afq[ks] = *(const bf16x8*)&Qs[(w * 16 + lrow) * 200 + ks * 32 + quad * 8];

    f32x4 Oacc[8];
#pragma unroll
    for (int nt = 0; nt < 8; ++nt) Oacc[nt] = (f32x4){0.f, 0.f, 0.f, 0.f};
    float m_run[4] = {-1e30f, -1e30f, -1e30f, -1e30f};
    float l_run[4] = {0.f, 0.f, 0.f, 0.f};

    const short* KgH = Kg + (size_t)h * (2048 * 192);
    const short* VgH = Vg + (size_t)h * (128 * 2048);

    for (int kt = 0; kt <= qb; ++kt) {
        __syncthreads();   // prev iteration's frag reads done
#pragma unroll
        for (int it = 0; it < 6; ++it) {
            const int id = tid + 256 * it;
            const int r = id / 24, g = id % 24;
            *(uint4*)&Ks[r * 200 + g * 8] =
                *(const uint4*)&KgH[(size_t)(kt * 64 + r) * 192 + g * 8];
        }
#pragma unroll
        for (int it = 0; it < 4; ++it) {
            const int id = tid + 256 * it;
            const int rv = id >> 3, g = id & 7;
            *(uint4*)&Vt[rv * 72 + g * 8] =
                *(const uint4*)&VgH[(size_t)rv * 2048 + kt * 64 + g * 8];
        }
        __syncthreads();

        // scores S[16q x 64k]
        f32x4 Sc[4];
#pragma unroll
        for (int nt = 0; nt < 4; ++nt) Sc[nt] = (f32x4){0.f, 0.f, 0.f, 0.f};
#pragma unroll
        for (int ks = 0; ks < 6; ++ks)
#pragma unroll
            for (int nt = 0; nt < 4; ++nt) {
                bf16x8 bk = *(const bf16x8*)&Ks[(nt * 16 + lrow) * 200 + ks * 32 + quad * 8];
                Sc[nt] = __builtin_amdgcn_mfma_f32_16x16x32_bf16(afq[ks], bk, Sc[nt], 0, 0, 0);
            }

        if (kt == qb) {   // diagonal tile: causal mask
            const int qrow = w * 16 + quad * 4;
#pragma unroll
            for (int nt = 0; nt < 4; ++nt)
#pragma unroll
                for (int i = 0; i < 4; ++i)
                    if (nt * 16 + lrow > qrow + i) Sc[nt][i] = -1e30f;
        }

        float alpha[4];
#pragma unroll
        for (int i = 0; i < 4; ++i) {
            float m = fmaxf(fmaxf(Sc[0][i], Sc[1][i]), fmaxf(Sc[2][i], Sc[3][i]));
            m = fmaxf(m, __shfl_xor(m, 1));
            m = fmaxf(m, __shfl_xor(m, 2));
            m = fmaxf(m, __shfl_xor(m, 4));
            m = fmaxf(m, __shfl_xor(m, 8));
            const float mn = fmaxf(m_run[i], m);
            alpha[i] = expf(m_run[i] - mn);
            m_run[i] = mn;
        }

        float rs[4] = {0.f, 0.f, 0.f, 0.f};
#pragma unroll
        for (int nt = 0; nt < 4; ++nt)
#pragma unroll
            for (int i = 0; i < 4; ++i) {
                const float p = expf(Sc[nt][i] - m_run[i]);
                rs[i] += p;
                Ps[(w * 16 + quad * 4 + i) * 72 + nt * 16 + lrow] = f2bf(p);
            }
#pragma unroll
        for (int i = 0; i < 4; ++i) {
            float r = rs[i];
            r += __shfl_xor(r, 1);
            r += __shfl_xor(r, 2);
            r += __shfl_xor(r, 4);
            r += __shfl_xor(r, 8);
            l_run[i] = l_run[i] * alpha[i] + r;
        }

#pragma unroll
        for (int nt = 0; nt < 8; ++nt)
#pragma unroll
            for (int i = 0; i < 4; ++i) Oacc[nt][i] *= alpha[i];

        // PV: O += P @ V  (Ps rows are this wave's own band -> no barrier)
#pragma unroll
        for (int ks2 = 0; ks2 < 2; ++ks2) {
            bf16x8 ap = *(const bf16x8*)&Ps[(w * 16 + lrow) * 72 + ks2 * 32 + quad * 8];
#pragma unroll
            for (int nt = 0; nt < 8; ++nt) {
                bf16x8 bv = *(const bf16x8*)&Vt[(nt * 16 + lrow) * 72 + ks2 * 32 + quad * 8];
                Oacc[nt] = __builtin_amdgcn_mfma_f32_16x16x32_bf16(ap, bv, Oacc[nt], 0, 0, 0);
            }
        }
    }

    float invl[4];
#pragma unroll
    for (int i = 0; i < 4; ++i) invl[i] = 1.f / l_run[i];
#pragma unroll
    for (int nt = 0; nt < 8; ++nt)
#pragma unroll
        for (int i = 0; i < 4; ++i)
            aout[(size_t)(q0 + w * 16 + quad * 4 + i) * AOROW + h * 128 + nt * 16 + lrow]
                = Oacc[nt][i] * invl[i];
}

// ---------------------------------------------------------------------------
extern "C" void kernel_launch(void* const* d_in, const int* in_sizes, int n_in,
                              void* d_out, int out_size, void* d_ws, size_t ws_size,
                              hipStream_t stream)
{
    const int*   positions = (const int*)d_in[0];
    const float* hidden    = (const float*)d_in[1];
    const float* w_qa      = (const float*)d_in[2];
    const float* gamma_q   = (const float*)d_in[3];
    const float* w_qb      = (const float*)d_in[4];
    const float* w_kva     = (const float*)d_in[5];
    const float* gamma_kv  = (const float*)d_in[6];
    const float* w_kvb     = (const float*)d_in[7];
    const float* w_o       = (const float*)d_in[8];
    float*       out       = (float*)d_out;

    // Workspace layout (~143 MB)
    float* qa   = (float*)d_ws;                         // [2048,1536] f32
    float* qbuf = qa   + (size_t)T_SEQ * Q_LORA;        // [2048,6144] f32
    float* kvb  = qbuf + (size_t)T_SEQ * QROW;          // [2048,576]  f32
    short* Kg   = (short*)(kvb + (size_t)T_SEQ * KVD);  // [32][2048][192] bf16
    short* Vg   = Kg + (size_t)NH * 2048 * 192;         // [32][128][2048] bf16
    float* aout = (float*)(Vg + (size_t)NH * 128 * 2048); // [2048,4096] f32

    const dim3 blk(256);

    // 1) qa = hidden @ w_qa
    gemm_bf16<<<dim3(Q_LORA / 128, T_SEQ / 128), blk, 0, stream>>>(
        hidden, w_qa, qa, Q_LORA, HIDDEN, HIDDEN, Q_LORA, Q_LORA);
    // 2) rmsnorm(qa)
    rmsnorm_k<<<dim3(T_SEQ), blk, 0, stream>>>(qa, gamma_q, Q_LORA, Q_LORA);
    // 3) qbuf = qa @ w_qb
    gemm_bf16<<<dim3(QROW / 128, T_SEQ / 128), blk, 0, stream>>>(
        qa, w_qb, qbuf, QROW, Q_LORA, Q_LORA, QROW, QROW);
    // 4) kvb = hidden @ w_kva
    gemm_bf16<<<dim3((KVD + 127) / 128, T_SEQ / 128), blk, 0, stream>>>(
        hidden, w_kva, kvb, KVD, HIDDEN, HIDDEN, KVD, KVD);
    // 5) rmsnorm on kvb[:, :512]
    rmsnorm_k<<<dim3(T_SEQ), blk, 0, stream>>>(kvb, gamma_kv, KV_LORA, KVD);
    // 6) RoPE k_pe -> broadcast into Kg pe cols (bf16)
    rope_k_bcast<<<dim3(T_SEQ * 32 / 256), blk, 0, stream>>>(kvb, positions, Kg);
    // 7) kv-up GEMM -> Kg nope cols + Vg (transposed), bf16
    gemm_kv<<<dim3(KVUPROW / 128, T_SEQ / 128), blk, 0, stream>>>(
        kvb, w_kvb, Kg, Vg, KVD, KVUPROW);
    // 8) RoPE q_pe in place (fp32 qbuf)
    rope_q_k<<<dim3(T_SEQ * NH * 32 / 256), blk, 0, stream>>>(qbuf, positions);
    // 9) MFMA flash attention -> aout
    attn_mfma<<<dim3(NH, T_SEQ / 64), blk, 0, stream>>>(qbuf, Kg, Vg, aout);
    // 10) out = aout @ w_o
    gemm_bf16<<<dim3(HIDDEN / 128, T_SEQ / 128), blk, 0, stream>>>(
        aout, w_o, out, HIDDEN, AOROW, AOROW, HIDDEN, HIDDEN);
}

// Round 5
// 1264.383 us; speedup vs baseline: 6.7080x; 1.3506x over previous
//
#include <hip/hip_runtime.h>
#include <hip/hip_bf16.h>
#include <cstdint>
#include <cstddef>

#define T_SEQ   2048
#define HIDDEN  5120
#define NH      32
#define DQ      128
#define DR      64
#define DV      128
#define Q_LORA  1536
#define KV_LORA 512
#define QD      (DQ + DR)          // 192
#define KVD     (KV_LORA + DR)     // 576
#define QROW    (NH * QD)          // 6144
#define KVUPROW (NH * (DQ + DV))   // 8192
#define AOROW   (NH * DV)          // 4096

typedef short bf16x8 __attribute__((ext_vector_type(8)));   // 8 bf16 raw (4 VGPRs)
typedef float f32x4  __attribute__((ext_vector_type(4)));

// fp32 -> bf16 raw bits, round-to-nearest-even
static __device__ __forceinline__ short f2bf(float f)
{
    union { float f; unsigned u; } v; v.f = f;
    unsigned r = v.u + 0x7FFFu + ((v.u >> 16) & 1u);
    return (short)(r >> 16);
}
static __device__ __forceinline__ float bf2f(short s)
{
    union { unsigned u; float f; } v;
    v.u = ((unsigned)(unsigned short)s) << 16;
    return v.f;
}

// ---------------------------------------------------------------------------
// Elementwise fp32 -> bf16 (n % 2048 == 0)
// ---------------------------------------------------------------------------
__global__ __launch_bounds__(256) void conv_bf(
    const float* __restrict__ src, short* __restrict__ dst)
{
    const size_t i = ((size_t)blockIdx.x * 256 + threadIdx.x) * 8;
    float4 a = *(const float4*)&src[i];
    float4 b = *(const float4*)&src[i + 4];
    union { short s[8]; uint4 u; } o;
    o.s[0] = f2bf(a.x); o.s[1] = f2bf(a.y); o.s[2] = f2bf(a.z); o.s[3] = f2bf(a.w);
    o.s[4] = f2bf(b.x); o.s[5] = f2bf(b.y); o.s[6] = f2bf(b.z); o.s[7] = f2bf(b.w);
    *(uint4*)&dst[i] = o.u;
}

// ---------------------------------------------------------------------------
// Transpose + convert: src[K][N] f32 -> dst[N][K] bf16. 32x32 tiles, 256 thr.
// K % 32 == 0, N % 32 == 0 (true for all five weights).
// ---------------------------------------------------------------------------
__global__ __launch_bounds__(256) void tr_f32_bf16(
    const float* __restrict__ src, short* __restrict__ dst, int K, int N)
{
    const int k0 = blockIdx.x * 32, n0 = blockIdx.y * 32;
    __shared__ float t[32][33];
    const int tid = threadIdx.x;
    {
        const int r = tid >> 3, c4 = (tid & 7) * 4;
        float4 v = *(const float4*)&src[(size_t)(k0 + r) * N + n0 + c4];
        t[r][c4 + 0] = v.x; t[r][c4 + 1] = v.y;
        t[r][c4 + 2] = v.z; t[r][c4 + 3] = v.w;
    }
    __syncthreads();
    {
        const int n = tid >> 3, k4 = (tid & 7) * 4;
        union { short s[4]; uint2 u; } o;
#pragma unroll
        for (int j = 0; j < 4; ++j) o.s[j] = f2bf(t[k4 + j][n]);
        *(uint2*)&dst[(size_t)(n0 + n) * K + k0 + k4] = o.u;
    }
}

// ---------------------------------------------------------------------------
// bf16 MFMA GEMM, B pre-transposed: C[M,N] = A[M,K](bf16) @ BT[N,K](bf16)^T.
// 128x128 tile, BK=64, 4 waves 2x2 (64x64/wave), 4x4 16x16x32 MFMA, 2 k-steps.
// Register double-buffer: next tile's global loads issued after the LDS store,
// overlapping the 32-MFMA compute phase. LDS stride 72 shorts -> <=2-way (free).
// Output: fp32 (Cb==null) or bf16 (Cb!=null). M%128, K%64; N guarded.
// ---------------------------------------------------------------------------
__global__ __launch_bounds__(256) void gemm_bt(
    const short* __restrict__ A, const short* __restrict__ BT,
    float* __restrict__ Cf, short* __restrict__ Cb, int N, int K,
    int lda, int ldbt, int ldc)
{
    __shared__ short As[128 * 72];
    __shared__ short Bs[128 * 72];

    const int tid  = threadIdx.x;
    const int bm   = blockIdx.y * 128;
    const int bn   = blockIdx.x * 128;
    const int w    = tid >> 6;
    const int l    = tid & 63;
    const int wm   = (w >> 1) * 64;
    const int wn   = (w & 1) * 64;
    const int quad = l >> 4;
    const int lrow = l & 15;

    f32x4 acc[4][4];
#pragma unroll
    for (int mt = 0; mt < 4; ++mt)
#pragma unroll
        for (int nt = 0; nt < 4; ++nt)
            acc[mt][nt] = (f32x4){0.f, 0.f, 0.f, 0.f};

    uint4 pa[4], pb[4];
#pragma unroll
    for (int i = 0; i < 4; ++i) {                 // prologue loads, k0 = 0
        const int id = tid + 256 * i;
        const int r = id >> 3, c8 = (id & 7) * 8;
        pa[i] = *(const uint4*)&A[(size_t)(bm + r) * lda + c8];
        pb[i] = (bn + r < N) ? *(const uint4*)&BT[(size_t)(bn + r) * ldbt + c8]
                             : make_uint4(0, 0, 0, 0);
    }

    for (int k0 = 0; k0 < K; k0 += 64) {
        __syncthreads();                          // previous frag reads done
#pragma unroll
        for (int i = 0; i < 4; ++i) {
            const int id = tid + 256 * i;
            const int r = id >> 3, c8 = (id & 7) * 8;
            *(uint4*)&As[r * 72 + c8] = pa[i];
            *(uint4*)&Bs[r * 72 + c8] = pb[i];
        }
        if (k0 + 64 < K) {                        // prefetch next tile
#pragma unroll
            for (int i = 0; i < 4; ++i) {
                const int id = tid + 256 * i;
                const int r = id >> 3, c8 = (id & 7) * 8;
                pa[i] = *(const uint4*)&A[(size_t)(bm + r) * lda + k0 + 64 + c8];
                pb[i] = (bn + r < N)
                    ? *(const uint4*)&BT[(size_t)(bn + r) * ldbt + k0 + 64 + c8]
                    : make_uint4(0, 0, 0, 0);
            }
        }
        __syncthreads();

#pragma unroll
        for (int ks = 0; ks < 2; ++ks) {
            bf16x8 af[4], bfr[4];
#pragma unroll
            for (int mt = 0; mt < 4; ++mt)
                af[mt] = *(const bf16x8*)&As[(wm + mt * 16 + lrow) * 72 + ks * 32 + quad * 8];
#pragma unroll
            for (int nt = 0; nt < 4; ++nt)
                bfr[nt] = *(const bf16x8*)&Bs[(wn + nt * 16 + lrow) * 72 + ks * 32 + quad * 8];
#pragma unroll
            for (int mt = 0; mt < 4; ++mt)
#pragma unroll
                for (int nt = 0; nt < 4; ++nt)
                    acc[mt][nt] = __builtin_amdgcn_mfma_f32_16x16x32_bf16(
                        af[mt], bfr[nt], acc[mt][nt], 0, 0, 0);
        }
    }

    // C/D layout: col = lane&15, row = quad*4 + i
    if (Cb == nullptr) {
#pragma unroll
        for (int mt = 0; mt < 4; ++mt)
#pragma unroll
            for (int i = 0; i < 4; ++i) {
                const int row = bm + wm + mt * 16 + quad * 4 + i;
                float* crow = Cf + (size_t)row * ldc;
#pragma unroll
                for (int nt = 0; nt < 4; ++nt) {
                    const int col = bn + wn + nt * 16 + lrow;
                    if (col < N) crow[col] = acc[mt][nt][i];
                }
            }
    } else {
#pragma unroll
        for (int mt = 0; mt < 4; ++mt)
#pragma unroll
            for (int i = 0; i < 4; ++i) {
                const int row = bm + wm + mt * 16 + quad * 4 + i;
                short* crow = Cb + (size_t)row * ldc;
#pragma unroll
                for (int nt = 0; nt < 4; ++nt) {
                    const int col = bn + wn + nt * 16 + lrow;
                    if (col < N) crow[col] = f2bf(acc[mt][nt][i]);
                }
            }
    }
}

// ---------------------------------------------------------------------------
// kv-up GEMM (same structure), epilogue into attention layouts:
//   cols h*256+d, d<128  -> Kg[h][row][d]   (bf16)
//   cols h*256+128+dv    -> Vg[h][dv][row]  (bf16, transposed)
// A = kvc_bf [2048][512] bf16, BT = w_kvbT [8192][512] bf16, K=512, N=8192.
// ---------------------------------------------------------------------------
__global__ __launch_bounds__(256) void gemm_kv(
    const short* __restrict__ A, const short* __restrict__ BT,
    short* __restrict__ Kg, short* __restrict__ Vg)
{
    __shared__ short As[128 * 72];
    __shared__ short Bs[128 * 72];

    const int tid  = threadIdx.x;
    const int bm   = blockIdx.y * 128;
    const int bn   = blockIdx.x * 128;
    const int w    = tid >> 6;
    const int l    = tid & 63;
    const int wm   = (w >> 1) * 64;
    const int wn   = (w & 1) * 64;
    const int quad = l >> 4;
    const int lrow = l & 15;

    f32x4 acc[4][4];
#pragma unroll
    for (int mt = 0; mt < 4; ++mt)
#pragma unroll
        for (int nt = 0; nt < 4; ++nt)
            acc[mt][nt] = (f32x4){0.f, 0.f, 0.f, 0.f};

    uint4 pa[4], pb[4];
#pragma unroll
    for (int i = 0; i < 4; ++i) {
        const int id = tid + 256 * i;
        const int r = id >> 3, c8 = (id & 7) * 8;
        pa[i] = *(const uint4*)&A[(size_t)(bm + r) * KV_LORA + c8];
        pb[i] = *(const uint4*)&BT[(size_t)(bn + r) * KV_LORA + c8];
    }

    for (int k0 = 0; k0 < KV_LORA; k0 += 64) {
        __syncthreads();
#pragma unroll
        for (int i = 0; i < 4; ++i) {
            const int id = tid + 256 * i;
            const int r = id >> 3, c8 = (id & 7) * 8;
            *(uint4*)&As[r * 72 + c8] = pa[i];
            *(uint4*)&Bs[r * 72 + c8] = pb[i];
        }
        if (k0 + 64 < KV_LORA) {
#pragma unroll
            for (int i = 0; i < 4; ++i) {
                const int id = tid + 256 * i;
                const int r = id >> 3, c8 = (id & 7) * 8;
                pa[i] = *(const uint4*)&A[(size_t)(bm + r) * KV_LORA + k0 + 64 + c8];
                pb[i] = *(const uint4*)&BT[(size_t)(bn + r) * KV_LORA + k0 + 64 + c8];
            }
        }
        __syncthreads();

#pragma unroll
        for (int ks = 0; ks < 2; ++ks) {
            bf16x8 af[4], bfr[4];
#pragma unroll
            for (int mt = 0; mt < 4; ++mt)
                af[mt] = *(const bf16x8*)&As[(wm + mt * 16 + lrow) * 72 + ks * 32 + quad * 8];
#pragma unroll
            for (int nt = 0; nt < 4; ++nt)
                bfr[nt] = *(const bf16x8*)&Bs[(wn + nt * 16 + lrow) * 72 + ks * 32 + quad * 8];
#pragma unroll
            for (int mt = 0; mt < 4; ++mt)
#pragma unroll
                for (int nt = 0; nt < 4; ++nt)
                    acc[mt][nt] = __builtin_amdgcn_mfma_f32_16x16x32_bf16(
                        af[mt], bfr[nt], acc[mt][nt], 0, 0, 0);
        }
    }

    const int  h     = bn >> 8;
    const bool vhalf = (bn & 128) != 0;
    if (!vhalf) {
        short* KgH = Kg + (size_t)h * (2048 * 192);
#pragma unroll
        for (int mt = 0; mt < 4; ++mt)
#pragma unroll
            for (int i = 0; i < 4; ++i) {
                const int row = bm + wm + mt * 16 + quad * 4 + i;
#pragma unroll
                for (int nt = 0; nt < 4; ++nt) {
                    const int d = wn + nt * 16 + lrow;
                    KgH[(size_t)row * 192 + d] = f2bf(acc[mt][nt][i]);
                }
            }
    } else {
        short* VgH = Vg + (size_t)h * (128 * 2048);
#pragma unroll
        for (int mt = 0; mt < 4; ++mt)
#pragma unroll
            for (int nt = 0; nt < 4; ++nt) {
                const int dv   = wn + nt * 16 + lrow;
                const int rowb = bm + wm + mt * 16 + quad * 4;
                union { short s[4]; uint2 u; } t;
                t.s[0] = f2bf(acc[mt][nt][0]); t.s[1] = f2bf(acc[mt][nt][1]);
                t.s[2] = f2bf(acc[mt][nt][2]); t.s[3] = f2bf(acc[mt][nt][3]);
                *(uint2*)&VgH[(size_t)dv * 2048 + rowb] = t.u;
            }
    }
}

// ---------------------------------------------------------------------------
// RMSNorm: fp32 in (in_stride) -> bf16 out (out_stride), first `len` cols.
// ---------------------------------------------------------------------------
__global__ __launch_bounds__(256) void rmsnorm_bf(
    const float* __restrict__ x, const float* __restrict__ g,
    short* __restrict__ y, int len, int in_stride, int out_stride)
{
    const float* xr = x + (size_t)blockIdx.x * in_stride;
    short*       yr = y + (size_t)blockIdx.x * out_stride;
    float ss = 0.f;
    for (int i = threadIdx.x; i < len; i += 256) {
        float v = xr[i];
        ss += v * v;
    }
#pragma unroll
    for (int off = 32; off > 0; off >>= 1) ss += __shfl_down(ss, off);
    __shared__ float red[4];
    if ((threadIdx.x & 63) == 0) red[threadIdx.x >> 6] = ss;
    __syncthreads();
    float tot = red[0] + red[1] + red[2] + red[3];
    float scale = rsqrtf(tot / (float)len + 1e-6f);
    for (int i = threadIdx.x; i < len; i += 256)
        yr[i] = f2bf(xr[i] * scale * g[i]);
}

// ---------------------------------------------------------------------------
// RoPE (GPT-J interleaved rotate, NEOX concatenated cos/sin)
// ---------------------------------------------------------------------------
#define ROPE_LN_THETA_OVER_32 0.28782313662425575f  // ln(10000)/32

__device__ __forceinline__ void rope_pair(float p, int i, float& x0, float& x1)
{
    const int   j0 = (2 * i) & 31;
    const int   j1 = (2 * i + 1) & 31;
    const float a0 = p * expf(-(float)j0 * ROPE_LN_THETA_OVER_32);
    const float a1 = p * expf(-(float)j1 * ROPE_LN_THETA_OVER_32);
    const float r0 = x0 * cosf(a0) - x1 * sinf(a0);
    const float r1 = x1 * cosf(a1) + x0 * sinf(a1);
    x0 = r0; x1 = r1;
}

// q_pe RoPE in place on bf16 qbuf
__global__ __launch_bounds__(256) void rope_q_bf(
    short* __restrict__ qb, const int* __restrict__ pos)
{
    const int idx = blockIdx.x * 256 + threadIdx.x;  // t*1024 + h*32 + i
    const int i = idx & 31;
    const int h = (idx >> 5) & 31;
    const int t = idx >> 10;
    short* base = qb + (size_t)t * QROW + h * QD + DQ;
    float x0 = bf2f(base[2 * i]), x1 = bf2f(base[2 * i + 1]);
    rope_pair((float)pos[t], i, x0, x1);
    union { short s[2]; unsigned u; } o;
    o.s[0] = f2bf(x0); o.s[1] = f2bf(x1);
    *(unsigned*)&base[2 * i] = o.u;
}

// k_pe RoPE: read kvb f32 pe cols, rotate, broadcast to all heads' Kg cols
__global__ __launch_bounds__(256) void rope_k_bcast(
    const float* __restrict__ kvb, const int* __restrict__ pos,
    short* __restrict__ Kg)
{
    const int idx = blockIdx.x * 256 + threadIdx.x;  // t*32 + i
    const int i = idx & 31;
    const int t = idx >> 5;
    const float* base = kvb + (size_t)t * KVD + KV_LORA;
    float x0 = base[2 * i], x1 = base[2 * i + 1];
    rope_pair((float)pos[t], i, x0, x1);
    union { short s[2]; unsigned u; } pk;
    pk.s[0] = f2bf(x0); pk.s[1] = f2bf(x1);
    for (int h = 0; h < NH; ++h)
        *(unsigned*)&Kg[((size_t)h * 2048 + t) * 192 + 128 + 2 * i] = pk.u;
}

// ---------------------------------------------------------------------------
// MFMA flash attention (round-4 structure). bf16 Q in, bf16 out.
// Scale applied to scores (not Q).
// ---------------------------------------------------------------------------
__global__ __launch_bounds__(256) void attn_mfma(
    const short* __restrict__ qb, const short* __restrict__ Kg,
    const short* __restrict__ Vg, short* __restrict__ aout)
{
    const int h  = blockIdx.x;
    const int qb_ = blockIdx.y;
    const int q0 = qb_ * 64;

    __shared__ short Qs[64 * 200];
    __shared__ short Ks[64 * 200];
    __shared__ short Vt[128 * 72];
    __shared__ short Ps[64 * 72];

    const int tid  = threadIdx.x;
    const int w    = tid >> 6;
    const int l    = tid & 63;
    const int quad = l >> 4;
    const int lrow = l & 15;

    const float scale = 0.07216878364870322f;  // 1/sqrt(192)

    // Q tile -> LDS (straight bf16 copy)
#pragma unroll
    for (int it = 0; it < 6; ++it) {
        const int id = tid + 256 * it;
        const int r = id / 24, g = id % 24;
        *(uint4*)&Qs[r * 200 + g * 8] =
            *(const uint4*)&qb[(size_t)(q0 + r) * QROW + h * QD + g * 8];
    }
    __syncthreads();

    bf16x8 afq[6];
#pragma unroll
    for (int ks = 0; ks < 6; ++ks)
        afq[ks] = *(const bf16x8*)&Qs[(w * 16 + lrow) * 200 + ks * 32 + quad * 8];

    f32x4 Oacc[8];
#pragma unroll
    for (int nt = 0; nt < 8; ++nt) Oacc[nt] = (f32x4){0.f, 0.f, 0.f, 0.f};
    float m_run[4] = {-1e30f, -1e30f, -1e30f, -1e30f};
    float l_run[4] = {0.f, 0.f, 0.f, 0.f};

    const short* KgH = Kg + (size_t)h * (2048 * 192);
    const short* VgH = Vg + (size_t)h * (128 * 2048);

    for (int kt = 0; kt <= qb_; ++kt) {
        __syncthreads();
#pragma unroll
        for (int it = 0; it < 6; ++it) {
            const int id = tid + 256 * it;
            const int r = id / 24, g = id % 24;
            *(uint4*)&Ks[r * 200 + g * 8] =
                *(const uint4*)&KgH[(size_t)(kt * 64 + r) * 192 + g * 8];
        }
#pragma unroll
        for (int it = 0; it < 4; ++it) {
            const int id = tid + 256 * it;
            const int rv = id >> 3, g = id & 7;
            *(uint4*)&Vt[rv * 72 + g * 8] =
                *(const uint4*)&VgH[(size_t)rv * 2048 + kt * 64 + g * 8];
        }
        __syncthreads();

        f32x4 Sc[4];
#pragma unroll
        for (int nt = 0; nt < 4; ++nt) Sc[nt] = (f32x4){0.f, 0.f, 0.f, 0.f};
#pragma unroll
        for (int ks = 0; ks < 6; ++ks)
#pragma unroll
            for (int nt = 0; nt < 4; ++nt) {
                bf16x8 bk = *(const bf16x8*)&Ks[(nt * 16 + lrow) * 200 + ks * 32 + quad * 8];
                Sc[nt] = __builtin_amdgcn_mfma_f32_16x16x32_bf16(afq[ks], bk, Sc[nt], 0, 0, 0);
            }
#pragma unroll
        for (int nt = 0; nt < 4; ++nt)
#pragma unroll
            for (int i = 0; i < 4; ++i) Sc[nt][i] *= scale;

        if (kt == qb_) {   // diagonal tile: causal mask
            const int qrow = w * 16 + quad * 4;
#pragma unroll
            for (int nt = 0; nt < 4; ++nt)
#pragma unroll
                for (int i = 0; i < 4; ++i)
                    if (nt * 16 + lrow > qrow + i) Sc[nt][i] = -1e30f;
        }

        float alpha[4];
#pragma unroll
        for (int i = 0; i < 4; ++i) {
            float m = fmaxf(fmaxf(Sc[0][i], Sc[1][i]), fmaxf(Sc[2][i], Sc[3][i]));
            m = fmaxf(m, __shfl_xor(m, 1));
            m = fmaxf(m, __shfl_xor(m, 2));
            m = fmaxf(m, __shfl_xor(m, 4));
            m = fmaxf(m, __shfl_xor(m, 8));
            const float mn = fmaxf(m_run[i], m);
            alpha[i] = expf(m_run[i] - mn);
            m_run[i] = mn;
        }

        float rs[4] = {0.f, 0.f, 0.f, 0.f};
#pragma unroll
        for (int nt = 0; nt < 4; ++nt)
#pragma unroll
            for (int i = 0; i < 4; ++i) {
                const float p = expf(Sc[nt][i] - m_run[i]);
                rs[i] += p;
                Ps[(w * 16 + quad * 4 + i) * 72 + nt * 16 + lrow] = f2bf(p);
            }
#pragma unroll
        for (int i = 0; i < 4; ++i) {
            float r = rs[i];
            r += __shfl_xor(r, 1);
            r += __shfl_xor(r, 2);
            r += __shfl_xor(r, 4);
            r += __shfl_xor(r, 8);
            l_run[i] = l_run[i] * alpha[i] + r;
        }

#pragma unroll
        for (int nt = 0; nt < 8; ++nt)
#pragma unroll
            for (int i = 0; i < 4; ++i) Oacc[nt][i] *= alpha[i];

#pragma unroll
        for (int ks2 = 0; ks2 < 2; ++ks2) {
            bf16x8 ap = *(const bf16x8*)&Ps[(w * 16 + lrow) * 72 + ks2 * 32 + quad * 8];
#pragma unroll
            for (int nt = 0; nt < 8; ++nt) {
                bf16x8 bv = *(const bf16x8*)&Vt[(nt * 16 + lrow) * 72 + ks2 * 32 + quad * 8];
                Oacc[nt] = __builtin_amdgcn_mfma_f32_16x16x32_bf16(ap, bv, Oacc[nt], 0, 0, 0);
            }
        }
    }

    float invl[4];
#pragma unroll
    for (int i = 0; i < 4; ++i) invl[i] = 1.f / l_run[i];
#pragma unroll
    for (int nt = 0; nt < 8; ++nt)
#pragma unroll
        for (int i = 0; i < 4; ++i)
            aout[(size_t)(q0 + w * 16 + quad * 4 + i) * AOROW + h * 128 + nt * 16 + lrow]
                = f2bf(Oacc[nt][i] * invl[i]);
}

// ---------------------------------------------------------------------------
extern "C" void kernel_launch(void* const* d_in, const int* in_sizes, int n_in,
                              void* d_out, int out_size, void* d_ws, size_t ws_size,
                              hipStream_t stream)
{
    const int*   positions = (const int*)d_in[0];
    const float* hidden    = (const float*)d_in[1];
    const float* w_qa      = (const float*)d_in[2];
    const float* gamma_q   = (const float*)d_in[3];
    const float* w_qb      = (const float*)d_in[4];
    const float* w_kva     = (const float*)d_in[5];
    const float* gamma_kv  = (const float*)d_in[6];
    const float* w_kvb     = (const float*)d_in[7];
    const float* w_o       = (const float*)d_in[8];
    float*       out       = (float*)d_out;

    // Workspace layout (~160 MB). wT reused for each weight's B^T.
    short* wT      = (short*)d_ws;                 // max 5120*4096 = 20,971,520 shorts
    short* hid_bf  = wT      + (size_t)20971520;   // [2048][5120]
    short* qbuf_bf = hid_bf  + (size_t)T_SEQ * HIDDEN;   // [2048][6144]
    short* Kg      = qbuf_bf + (size_t)T_SEQ * QROW;     // [32][2048][192]
    short* Vg      = Kg      + (size_t)NH * 2048 * 192;  // [32][128][2048]
    short* aout_bf = Vg      + (size_t)NH * 128 * 2048;  // [2048][4096]
    float* qa      = (float*)aout_bf;              // alias (dead before aout written)
    short* qa_bf   = aout_bf + (size_t)T_SEQ * AOROW;    // [2048][1536]
    float* kvb     = (float*)(qa_bf + (size_t)T_SEQ * Q_LORA);  // [2048][576] f32
    short* kvc_bf  = (short*)(kvb + (size_t)T_SEQ * KVD);       // [2048][512]

    const dim3 blk(256);

    // 0) hidden -> bf16
    conv_bf<<<dim3(T_SEQ * HIDDEN / 8 / 256), blk, 0, stream>>>(hidden, hid_bf);

    // 1) qa = hidden @ w_qa   (fp32 out)
    tr_f32_bf16<<<dim3(HIDDEN / 32, Q_LORA / 32), blk, 0, stream>>>(w_qa, wT, HIDDEN, Q_LORA);
    gemm_bt<<<dim3(Q_LORA / 128, T_SEQ / 128), blk, 0, stream>>>(
        hid_bf, wT, qa, nullptr, Q_LORA, HIDDEN, HIDDEN, HIDDEN, Q_LORA);
    // 2) rmsnorm -> bf16
    rmsnorm_bf<<<dim3(T_SEQ), blk, 0, stream>>>(qa, gamma_q, qa_bf, Q_LORA, Q_LORA, Q_LORA);
    // 3) qbuf = qa_bf @ w_qb  (bf16 out)
    tr_f32_bf16<<<dim3(Q_LORA / 32, QROW / 32), blk, 0, stream>>>(w_qb, wT, Q_LORA, QROW);
    gemm_bt<<<dim3(QROW / 128, T_SEQ / 128), blk, 0, stream>>>(
        qa_bf, wT, nullptr, qbuf_bf, QROW, Q_LORA, Q_LORA, Q_LORA, QROW);
    // 4) kvb = hidden @ w_kva (fp32 out, N=576 guarded)
    tr_f32_bf16<<<dim3(HIDDEN / 32, KVD / 32), blk, 0, stream>>>(w_kva, wT, HIDDEN, KVD);
    gemm_bt<<<dim3((KVD + 127) / 128, T_SEQ / 128), blk, 0, stream>>>(
        hid_bf, wT, kvb, nullptr, KVD, HIDDEN, HIDDEN, HIDDEN, KVD);
    // 5) rmsnorm kvb[:, :512] -> kvc_bf
    rmsnorm_bf<<<dim3(T_SEQ), blk, 0, stream>>>(kvb, gamma_kv, kvc_bf, KV_LORA, KVD, KV_LORA);
    // 6) RoPE k_pe -> broadcast into Kg pe cols
    rope_k_bcast<<<dim3(T_SEQ * 32 / 256), blk, 0, stream>>>(kvb, positions, Kg);
    // 7) kv-up -> Kg nope + Vg transposed
    tr_f32_bf16<<<dim3(KV_LORA / 32, KVUPROW / 32), blk, 0, stream>>>(w_kvb, wT, KV_LORA, KVUPROW);
    gemm_kv<<<dim3(KVUPROW / 128, T_SEQ / 128), blk, 0, stream>>>(kvc_bf, wT, Kg, Vg);
    // 8) RoPE q_pe in place (bf16 qbuf)
    rope_q_bf<<<dim3(T_SEQ * NH * 32 / 256), blk, 0, stream>>>(qbuf_bf, positions);
    // 9) MFMA flash attention -> aout bf16
    attn_mfma<<<dim3(NH, T_SEQ / 64), blk, 0, stream>>>(qbuf_bf, Kg, Vg, aout_bf);
    // 10) out = aout @ w_o (fp32 out)
    tr_f32_bf16<<<dim3(AOROW / 32, HIDDEN / 32), blk, 0, stream>>>(w_o, wT, AOROW, HIDDEN);
    gemm_bt<<<dim3(HIDDEN / 128, T_SEQ / 128), blk, 0, stream>>>(
        aout_bf, wT, out, nullptr, HIDDEN, AOROW, AOROW, AOROW, HIDDEN);
}